// Round 1
// baseline (1167.535 us; speedup 1.0000x reference)
//
#include <hip/hip_runtime.h>
#include <hip/hip_bf16.h>

// CAPERNN_ContRoles_HPN — round 1: composed-weight restructuring + bf16 MFMA GEMMs.
// M = BN = 16384 rows, H=256, NH=4, HD=64, NA=15, NE=16, RD=8, NMOVE=6.

#define MROWS 16384

typedef __attribute__((ext_vector_type(8))) short short8;
typedef __attribute__((ext_vector_type(4))) float float4v;

__device__ __forceinline__ unsigned short f2b(float f) {
    __hip_bfloat16 h = __float2bfloat16(f);
    return *reinterpret_cast<unsigned short*>(&h);
}
__device__ __forceinline__ float b2f(unsigned short u) {
    __hip_bfloat16 h;
    *reinterpret_cast<unsigned short*>(&h) = u;
    return __bfloat162float(h);
}

// ---------------- prep: fp32 -> bf16 conversion ----------------
struct CvtTable {
    const float* src[15];
    unsigned short* dst[15];
    int n[15];
};
__global__ void cvt_kernel(CvtTable T) {
    int e = blockIdx.y;
    int i = (blockIdx.x * 256 + threadIdx.x) * 4;
    if (i >= T.n[e]) return;
    float4 v = *(const float4*)(T.src[e] + i);
    unsigned short* d = T.dst[e] + i;
    d[0] = f2b(v.x); d[1] = f2b(v.y); d[2] = f2b(v.z); d[3] = f2b(v.w);
}

// ---------------- prep: weight composition (fp32) ----------------
// Wo[i][j] = sum_k Wa[i][k] * Wb[k][j]   (Wa 256x256, Wb 256x32)
// bo[i]    = sum_k Wa[i][k] * bb[k]
struct CompTable {
    const float* Wa[5];
    const float* Wb[5];
    const float* bb[5];
    float* Wo[5];
    float* bo[5];
};
__global__ void compose_kernel(CompTable T) {
    int e = blockIdx.y;
    const float* Wa = T.Wa[e];
    const float* Wb = T.Wb[e];
    const float* bb = T.bb[e];
    for (int idx = threadIdx.x; idx < 64 * 33; idx += 256) {
        int i = blockIdx.x * 64 + idx / 33;
        int c = idx % 33;
        const float* wa = Wa + i * 256;
        float s = 0.f;
        if (c < 32) {
            for (int k = 0; k < 256; k++) s += wa[k] * Wb[k * 32 + c];
            T.Wo[e][i * 32 + c] = s;
        } else {
            for (int k = 0; k < 256; k++) s += wa[k] * bb[k];
            T.bo[e][i] = s;
        }
    }
}

// ---------------- bf16 MFMA GEMM: C[M x N] = A[M x K] @ W[N x K]^T (+bias)(+gelu) ----------------
// block tile 128x128, 4 waves (2x2), wave tile 64x64 = 4x4 mfma 16x16x32 tiles.
__global__ __launch_bounds__(256, 2)
void gemm_bf16(const unsigned short* __restrict__ A, int lda,
               const unsigned short* __restrict__ W,
               const float* __restrict__ bias,
               unsigned short* __restrict__ C, int ldc,
               int N, int K, int act) {
    __shared__ __align__(16) unsigned short As[128 * 40];
    __shared__ __align__(16) unsigned short Bs[128 * 40];
    int tid = threadIdx.x;
    int m0 = blockIdx.x * 128, n0 = blockIdx.y * 128;
    int wave = tid >> 6, lane = tid & 63;
    int wm = (wave & 1) * 64, wn = (wave >> 1) * 64;
    int l16 = lane & 15, quad = lane >> 4;

    float4v acc[4][4];
#pragma unroll
    for (int i = 0; i < 4; i++)
#pragma unroll
        for (int j = 0; j < 4; j++) acc[i][j] = (float4v){0.f, 0.f, 0.f, 0.f};

    for (int k0 = 0; k0 < K; k0 += 32) {
#pragma unroll
        for (int i = 0; i < 2; i++) {
            int s = tid + i * 256;       // 0..511
            int rr = s >> 2;             // tile row 0..127
            int sg = (s & 3) * 8;        // k seg {0,8,16,24}
            int k = k0 + sg;
            uint4 z = make_uint4(0u, 0u, 0u, 0u);
            uint4 va = (k < K) ? *(const uint4*)(A + (size_t)(m0 + rr) * lda + k) : z;
            *(uint4*)(&As[rr * 40 + sg]) = va;
            uint4 vb = (k < K) ? *(const uint4*)(W + (size_t)(n0 + rr) * K + k) : z;
            *(uint4*)(&Bs[rr * 40 + sg]) = vb;
        }
        __syncthreads();
        short8 a[4], b[4];
#pragma unroll
        for (int i = 0; i < 4; i++) {
            a[i] = *(const short8*)(&As[(wm + i * 16 + l16) * 40 + quad * 8]);
            b[i] = *(const short8*)(&Bs[(wn + i * 16 + l16) * 40 + quad * 8]);
        }
#pragma unroll
        for (int i = 0; i < 4; i++)
#pragma unroll
            for (int j = 0; j < 4; j++)
                acc[i][j] = __builtin_amdgcn_mfma_f32_16x16x32_bf16(a[i], b[j], acc[i][j], 0, 0, 0);
        __syncthreads();
    }
#pragma unroll
    for (int i = 0; i < 4; i++) {
#pragma unroll
        for (int j = 0; j < 4; j++) {
#pragma unroll
            for (int rr = 0; rr < 4; rr++) {
                int rowm = m0 + wm + i * 16 + quad * 4 + rr;
                int coln = wn + j * 16 + l16;
                float v = acc[i][j][rr];
                if (bias) v += bias[n0 + coln];
                if (act == 1) v = 0.5f * v * (1.f + erff(v * 0.70710678f));
                C[(size_t)rowm * ldc + n0 + coln] = f2b(v);
            }
        }
    }
}

// ---------------- LayerNorm in-place on bf16 buffer, blockDim.x == F ----------------
__global__ void ln_bf16(unsigned short* X, const float* g, const float* b, int F) {
    int row = blockIdx.x;
    int t = threadIdx.x;
    size_t idx = (size_t)row * F + t;
    float v = b2f(X[idx]);
    float s = v, q = v * v;
    for (int o = 32; o; o >>= 1) {
        s += __shfl_xor(s, o, 64);
        q += __shfl_xor(q, o, 64);
    }
    __shared__ float rs[4], rq[4];
    int w = t >> 6, nw = F >> 6;
    if ((t & 63) == 0) { rs[w] = s; rq[w] = q; }
    __syncthreads();
    float ts = 0.f, tq = 0.f;
    for (int i = 0; i < nw; i++) { ts += rs[i]; tq += rq[i]; }
    float mean = ts / F;
    float var = tq / F - mean * mean;
    float o = (v - mean) * rsqrtf(var + 1e-5f) * g[t] + b[t];
    X[idx] = f2b(o);
}

// ---------------- attention + pooling glue (8 rows/block, 32 lanes/row) ----------------
__device__ __forceinline__ void attn_half(int t, int nM, const float* feats /*[nM*33]*/,
                                          const float* qhL /*256*/,
                                          const float* Wk, const float* bk,
                                          const float* Wv, const float* bv,
                                          float* maskL, float* qks /*128*/, float* wfs /*128*/,
                                          float* attnL /*64*/, unsigned short* ctx) {
    if (t < nM) {
        const float* fr = feats + t * 33;
        bool nz = false;
        for (int d = 0; d < 32; d++) nz |= (fr[d] != 0.f);
        maskL[t] = nz ? 1.f : 0.f;
    }
    float qb[4];
#pragma unroll
    for (int h = 0; h < 4; h++) {
        const float* q = qhL + h * 64;
        float s = 0.f;
        for (int d = 0; d < 64; d++) s += q[d] * Wk[(h * 64 + d) * 32 + t];
        qks[h * 32 + t] = s;
        float p = q[t] * bk[h * 64 + t] + q[t + 32] * bk[h * 64 + 32 + t];
        for (int o = 16; o; o >>= 1) p += __shfl_xor(p, o, 32);
        qb[h] = p;
    }
#pragma unroll
    for (int h = 0; h < 4; h++) {
        float sc = -3.0e38f;
        if (t < nM) {
            const float* fr = feats + t * 33;
            float s = 0.f;
            for (int d = 0; d < 32; d++) s += qks[h * 32 + d] * fr[d];
            sc = (s + qb[h]) * 0.125f;                 // 1/sqrt(HD)
            if (maskL[t] == 0.f) sc = -1e9f;
        }
        float mx = sc;
        for (int o = 16; o; o >>= 1) mx = fmaxf(mx, __shfl_xor(mx, o, 32));
        float e = (t < nM) ? expf(sc - mx) : 0.f;
        float sm = e;
        for (int o = 16; o; o >>= 1) sm += __shfl_xor(sm, o, 32);
        if (t < nM) attnL[h * 16 + t] = e / sm;
    }
#pragma unroll
    for (int h = 0; h < 4; h++) {
        float s = 0.f;
        for (int m = 0; m < nM; m++) s += attnL[h * 16 + m] * feats[m * 33 + t];
        wfs[h * 32 + t] = s;
    }
    for (int it = 0; it < 8; it++) {
        int i = t + it * 32;
        float s = bv[i];
        const float* wr = wfs + (i >> 6) * 32;
        const float* vr = Wv + i * 32;
        for (int d = 0; d < 32; d++) s += wr[d] * vr[d];
        ctx[i] = f2b(s);
    }
}

__device__ __forceinline__ void pool_half(int t, int nM, const float* feats, const float* maskL,
                                          float* mf, const float* W, const float* B,
                                          unsigned short* out) {
    float cnt = 0.f;
    for (int m = 0; m < nM; m++) cnt += maskL[m];
    float bs = cnt > 0.f ? 1.f : 0.f;
    float s = 0.f;
    for (int m = 0; m < nM; m++) s += maskL[m] * feats[m * 33 + t];
    mf[t] = s / fmaxf(cnt, 1e-8f);
    for (int it = 0; it < 8; it++) {
        int i = t + it * 32;
        float v = bs * B[i];
        const float* w = W + i * 32;
        for (int d = 0; d < 32; d++) v += w[d] * mf[d];
        out[i] = f2b(v);
    }
}

__global__ __launch_bounds__(256)
void glue_attn(const float* __restrict__ allyf, const float* __restrict__ enemyf,
               const unsigned short* __restrict__ QH, const unsigned short* __restrict__ SE,
               const float* __restrict__ comp,
               const float* __restrict__ allyW, const float* __restrict__ allyB,
               const float* __restrict__ enW, const float* __restrict__ enB,
               unsigned short* __restrict__ CTX, unsigned short* __restrict__ FIN,
               unsigned short* __restrict__ PIN) {
    __shared__ float af[8][495];   // 15 x 33 padded
    __shared__ float ef[8][528];   // 16 x 33 padded
    __shared__ float qh[8][512];
    __shared__ float qks[8][128];
    __shared__ float wfs[8][128];
    __shared__ float attnL[8][64];
    __shared__ float amask[8][16];
    __shared__ float emask[8][16];
    __shared__ float mf[8][32];
    int tid = threadIdx.x;
    size_t rb = (size_t)blockIdx.x * 8;
    for (int idx = tid; idx < 3840; idx += 256) {
        int r = idx / 480, w = idx % 480;
        af[r][(w >> 5) * 33 + (w & 31)] = allyf[rb * 480 + idx];
    }
    for (int idx = tid; idx < 4096; idx += 256) {
        int r = idx >> 9, w = idx & 511;
        ef[r][(w >> 5) * 33 + (w & 31)] = enemyf[rb * 512 + idx];
    }
    for (int idx = tid; idx < 4096; idx += 256)
        qh[idx >> 9][idx & 511] = b2f(QH[rb * 512 + idx]);
    __syncthreads();

    int r = tid >> 5, t = tid & 31;
    size_t row = rb + r;
    const float* WkA = comp + 0;     const float* bkA = comp + 8192;
    const float* WvA = comp + 8448;  const float* bvA = comp + 16640;
    const float* WkE = comp + 16896; const float* bkE = comp + 25088;
    const float* WvE = comp + 25344; const float* bvE = comp + 33536;

    attn_half(t, 15, af[r], qh[r],       WkA, bkA, WvA, bvA, amask[r], qks[r], wfs[r], attnL[r], CTX + row * 512);
    attn_half(t, 16, ef[r], qh[r] + 256, WkE, bkE, WvE, bvE, emask[r], qks[r], wfs[r], attnL[r], CTX + row * 512 + 256);
    pool_half(t, 15, af[r], amask[r], mf[r], allyW, allyB, PIN + row * 768 + 256);
    pool_half(t, 16, ef[r], emask[r], mf[r], enW, enB, PIN + row * 768 + 512);
    for (int it = 0; it < 8; it++) {
        int i = t + it * 32;
        unsigned short u = SE[row * 256 + i];
        FIN[row * 768 + i] = u;
        PIN[row * 768 + i] = u;
    }
}

// ---------------- role head: r = LN8(tanh(T3n @ role_W2^T + b2)) -> Xb[:,256:264] ----------------
__global__ void glue_role(const unsigned short* __restrict__ T3, const float* __restrict__ W2,
                          const float* __restrict__ b2, const float* __restrict__ rg,
                          const float* __restrict__ rb, unsigned short* __restrict__ Xb) {
    __shared__ float t3[32][132];
    int tid = threadIdx.x;
    size_t base = (size_t)blockIdx.x * 4096;
    for (int idx = tid; idx < 4096; idx += 256)
        t3[idx >> 7][idx & 127] = b2f(T3[base + idx]);
    __syncthreads();
    int r = tid >> 3, t = tid & 7;
    size_t row = (size_t)blockIdx.x * 32 + r;
    float s = b2[t];
    const float* w = W2 + t * 128;
    for (int d = 0; d < 128; d++) s += w[d] * t3[r][d];
    float v = tanhf(s);
    float mean = v;
    for (int o = 4; o; o >>= 1) mean += __shfl_xor(mean, o, 8);
    mean *= 0.125f;
    float dv = v - mean, q = dv * dv;
    for (int o = 4; o; o >>= 1) q += __shfl_xor(q, o, 8);
    q *= 0.125f;
    float out = dv * rsqrtf(q + 1e-5f) * rg[t] + rb[t];
    Xb[row * 264 + 256 + t] = f2b(out);
}

// ---------------- GRU glue ----------------
__global__ void glue_gru(const unsigned short* __restrict__ GI, const unsigned short* __restrict__ GH,
                         const float* __restrict__ hp, float* __restrict__ hout,
                         unsigned short* __restrict__ XQ, const unsigned short* __restrict__ Xb) {
    size_t row = blockIdx.x;
    int i = threadIdx.x;
    size_t b = row * 768;
    float ir = b2f(GI[b + i]), iz = b2f(GI[b + 256 + i]), in_ = b2f(GI[b + 512 + i]);
    float hr = b2f(GH[b + i]), hz = b2f(GH[b + 256 + i]), hn = b2f(GH[b + 512 + i]);
    float rg = 1.f / (1.f + expf(-(ir + hr)));
    float zg = 1.f / (1.f + expf(-(iz + hz)));
    float ng = tanhf(in_ + rg * hn);
    float h = (1.f - zg) * ng + zg * hp[row * 256 + i];
    hout[row * 256 + i] = h;
    XQ[row * 264 + i] = f2b(h);
    if (i < 8) XQ[row * 264 + 256 + i] = Xb[row * 264 + 256 + i];
}

// ---------------- final heads: q_normal + q_interact ----------------
__global__ void glue_final(const unsigned short* __restrict__ QV, const float* __restrict__ hout,
                           const float* __restrict__ efeats, const float* __restrict__ Wkp,
                           const float* __restrict__ bkp, const float* __restrict__ qnW,
                           const float* __restrict__ qnb, float* __restrict__ Q) {
    __shared__ float qv[8][256];
    __shared__ float hc[8][256];
    __shared__ float ef[8][528];
    __shared__ float qws[8][32];
    int tid = threadIdx.x;
    size_t rb = (size_t)blockIdx.x * 8;
    for (int idx = tid; idx < 2048; idx += 256) {
        qv[idx >> 8][idx & 255] = b2f(QV[rb * 256 + idx]);
        hc[idx >> 8][idx & 255] = hout[rb * 256 + idx];
    }
    for (int idx = tid; idx < 4096; idx += 256) {
        int r = idx >> 9, w = idx & 511;
        ef[r][(w >> 5) * 33 + (w & 31)] = efeats[rb * 512 + idx];
    }
    __syncthreads();
    int r = tid >> 5, t = tid & 31;
    size_t row = rb + r;
    {
        float s = 0.f;
        for (int i = 0; i < 256; i++) s += qv[r][i] * Wkp[i * 32 + t];
        qws[r][t] = s;
    }
    float c0 = 0.f;
    for (int it = 0; it < 8; it++) { int i = t + it * 32; c0 += qv[r][i] * bkp[i]; }
    for (int o = 16; o; o >>= 1) c0 += __shfl_xor(c0, o, 32);
    float lg = 0.f, mk = 0.f;
    if (t < 16) {
        const float* fr = ef[r] + t * 33;
        bool nz = false;
        float s = 0.f;
        for (int d = 0; d < 32; d++) { nz |= (fr[d] != 0.f); s += qws[r][d] * fr[d]; }
        mk = nz ? 1.f : 0.f;
        lg = (s + c0) * 0.0625f;   // 1/sqrt(H)
    }
    float sv = mk * lg, cv = mk;
    for (int o = 16; o; o >>= 1) { sv += __shfl_xor(sv, o, 32); cv += __shfl_xor(cv, o, 32); }
    float mean = sv / fmaxf(cv, 1.f);
    if (t < 16) Q[row * 22 + 6 + t] = (mk > 0.f ? lg : -1e9f) - mean;
    if (t < 6) {
        float s = qnb[t];
        const float* w = qnW + t * 256;
        for (int d = 0; d < 256; d++) s += w[d] * hc[r][d];
        Q[row * 22 + t] = s;
    }
}

// ---------------- host orchestration ----------------
extern "C" void kernel_launch(void* const* d_in, const int* in_sizes, int n_in,
                              void* d_out, int out_size, void* d_ws, size_t ws_size,
                              hipStream_t stream) {
    const float* own_feats = (const float*)d_in[1];
    const float* ally_feats = (const float*)d_in[2];
    const float* enemy_feats = (const float*)d_in[3];
    const float* hidden = (const float*)d_in[4];
    const float* own_W = (const float*)d_in[5];   const float* own_b = (const float*)d_in[6];
    const float* ally_W = (const float*)d_in[7];  const float* ally_b = (const float*)d_in[8];
    const float* en_W = (const float*)d_in[9];    const float* en_b = (const float*)d_in[10];
    const float* aA_Wq = (const float*)d_in[11];  const float* aA_Wk = (const float*)d_in[12];
    const float* aA_Wv = (const float*)d_in[13];  const float* aA_Wo = (const float*)d_in[14];
    const float* aE_Wq = (const float*)d_in[15];  const float* aE_Wk = (const float*)d_in[16];
    const float* aE_Wv = (const float*)d_in[17];  const float* aE_Wo = (const float*)d_in[18];
    const float* fuse_W1 = (const float*)d_in[19]; const float* fuse_b1 = (const float*)d_in[20];
    const float* fuse_g1 = (const float*)d_in[21]; const float* fuse_be1 = (const float*)d_in[22];
    const float* fuse_W2 = (const float*)d_in[23]; const float* fuse_b2 = (const float*)d_in[24];
    const float* pool_W1 = (const float*)d_in[25]; const float* pool_b1 = (const float*)d_in[26];
    const float* pool_g1 = (const float*)d_in[27]; const float* pool_be1 = (const float*)d_in[28];
    const float* pool_W2 = (const float*)d_in[29]; const float* pool_b2 = (const float*)d_in[30];
    const float* role_W1 = (const float*)d_in[31]; const float* role_b1 = (const float*)d_in[32];
    const float* role_g1 = (const float*)d_in[33]; const float* role_be1 = (const float*)d_in[34];
    const float* role_W2 = (const float*)d_in[35]; const float* role_b2 = (const float*)d_in[36];
    const float* rln_g = (const float*)d_in[37];   const float* rln_b = (const float*)d_in[38];
    const float* gru_Wih = (const float*)d_in[39]; const float* gru_Whh = (const float*)d_in[40];
    const float* gru_bih = (const float*)d_in[41]; const float* gru_bhh = (const float*)d_in[42];
    const float* qn_W = (const float*)d_in[43];    const float* qn_b = (const float*)d_in[44];
    const float* qp_W = (const float*)d_in[45];    const float* kp_W = (const float*)d_in[46];

    char* w = (char*)d_ws;
    unsigned short* SEb  = (unsigned short*)(w + 0);
    unsigned short* QHb  = (unsigned short*)(w + 8388608);
    unsigned short* CTXb = (unsigned short*)(w + 25165824);
    unsigned short* FINb = (unsigned short*)(w + 41943040);
    unsigned short* PINb = (unsigned short*)(w + 67108864);
    unsigned short* Xb   = (unsigned short*)(w + 92274688);
    unsigned short* QVb  = (unsigned short*)(w + 100925440);
    unsigned short* HPb  = (unsigned short*)(w + 109314048);
    unsigned short* OWNb = (unsigned short*)(w + 117702656);
    unsigned short* WB   = (unsigned short*)(w + 118751232);
    float* COMP = (float*)(w + 121012224);
    // total ws use: ~121.2 MB

    unsigned short* T1b = SEb;                 // SE dead after glue_attn
    unsigned short* T2b = QHb;                 // QH dead after glue_attn
    unsigned short* POOLb = QHb + 2097152;
    unsigned short* T3b = QHb + 4194304;
    unsigned short* XQb = CTXb;                // CTX dead after Wo GEMMs
    unsigned short* GIb = PINb;                // PIN dead after pool1
    unsigned short* GHb = FINb;                // FIN dead after fuse1

    unsigned short* own_Wb   = WB + 0;
    unsigned short* aA_Wqb   = WB + 8192;
    unsigned short* aE_Wqb   = WB + 73728;
    unsigned short* aA_Wob   = WB + 139264;
    unsigned short* aE_Wob   = WB + 204800;
    unsigned short* fuse_W1b = WB + 270336;
    unsigned short* fuse_W2b = WB + 466944;
    unsigned short* pool_W1b = WB + 532480;
    unsigned short* pool_W2b = WB + 630784;
    unsigned short* role_W1b = WB + 647168;
    unsigned short* gru_Wihb = WB + 663552;
    unsigned short* gru_Whhb = WB + 866304;
    unsigned short* qp_Wb    = WB + 1062912;

    float* Qout = (float*)d_out;
    float* Hout = Qout + (size_t)MROWS * 22;

    CvtTable ct;
    {
        int i = 0;
        auto add = [&](const float* s, unsigned short* d, int n) { ct.src[i] = s; ct.dst[i] = d; ct.n[i] = n; i++; };
        add(own_W, own_Wb, 8192);
        add(aA_Wq, aA_Wqb, 65536);
        add(aE_Wq, aE_Wqb, 65536);
        add(aA_Wo, aA_Wob, 65536);
        add(aE_Wo, aE_Wob, 65536);
        add(fuse_W1, fuse_W1b, 196608);
        add(fuse_W2, fuse_W2b, 65536);
        add(pool_W1, pool_W1b, 98304);
        add(pool_W2, pool_W2b, 16384);
        add(role_W1, role_W1b, 16384);
        add(gru_Wih, gru_Wihb, 202752);
        add(gru_Whh, gru_Whhb, 196608);
        add(qp_W, qp_Wb, 67584);
        add(own_feats, OWNb, 524288);
        add(hidden, HPb, 4194304);
    }
    cvt_kernel<<<dim3(4096, 15), 256, 0, stream>>>(ct);

    CompTable cp;
    cp.Wa[0] = aA_Wk; cp.Wb[0] = ally_W; cp.bb[0] = ally_b; cp.Wo[0] = COMP + 0;     cp.bo[0] = COMP + 8192;
    cp.Wa[1] = aA_Wv; cp.Wb[1] = ally_W; cp.bb[1] = ally_b; cp.Wo[1] = COMP + 8448;  cp.bo[1] = COMP + 16640;
    cp.Wa[2] = aE_Wk; cp.Wb[2] = en_W;   cp.bb[2] = en_b;   cp.Wo[2] = COMP + 16896; cp.bo[2] = COMP + 25088;
    cp.Wa[3] = aE_Wv; cp.Wb[3] = en_W;   cp.bb[3] = en_b;   cp.Wo[3] = COMP + 25344; cp.bo[3] = COMP + 33536;
    cp.Wa[4] = kp_W;  cp.Wb[4] = en_W;   cp.bb[4] = en_b;   cp.Wo[4] = COMP + 33792; cp.bo[4] = COMP + 41984;
    compose_kernel<<<dim3(4, 5), 256, 0, stream>>>(cp);

    auto gemm = [&](const unsigned short* A, int lda, const unsigned short* Wm, const float* bias,
                    unsigned short* C, int ldc, int N, int K, int act) {
        gemm_bf16<<<dim3(MROWS / 128, N / 128), 256, 0, stream>>>(A, lda, Wm, bias, C, ldc, N, K, act);
    };

    gemm(OWNb, 32, own_Wb, own_b, SEb, 256, 256, 32, 0);                       // self_emb
    gemm(SEb, 256, aA_Wqb, nullptr, QHb, 512, 256, 256, 0);                    // qhA
    gemm(SEb, 256, aE_Wqb, nullptr, QHb + 256, 512, 256, 256, 0);              // qhE
    glue_attn<<<2048, 256, 0, stream>>>(ally_feats, enemy_feats, QHb, SEb, COMP,
                                        ally_W, ally_b, en_W, en_b, CTXb, FINb, PINb);
    gemm(CTXb, 512, aA_Wob, nullptr, FINb + 256, 768, 256, 256, 0);            // cA
    gemm(CTXb + 256, 512, aE_Wob, nullptr, FINb + 512, 768, 256, 256, 0);      // cE
    gemm(FINb, 768, fuse_W1b, fuse_b1, T1b, 256, 256, 768, 1);                 // fuse1 + gelu
    ln_bf16<<<MROWS, 256, 0, stream>>>(T1b, fuse_g1, fuse_be1, 256);
    gemm(T1b, 256, fuse_W2b, fuse_b2, Xb, 264, 256, 256, 0);                   // h0 -> X[:,0:256]
    gemm(PINb, 768, pool_W1b, pool_b1, T2b, 128, 128, 768, 1);                 // pool1 + gelu
    ln_bf16<<<MROWS, 128, 0, stream>>>(T2b, pool_g1, pool_be1, 128);
    gemm(T2b, 128, pool_W2b, pool_b2, POOLb, 128, 128, 128, 0);                // pooled
    gemm(POOLb, 128, role_W1b, role_b1, T3b, 128, 128, 128, 1);                // role1 + gelu
    ln_bf16<<<MROWS, 128, 0, stream>>>(T3b, role_g1, role_be1, 128);
    glue_role<<<512, 256, 0, stream>>>(T3b, role_W2, role_b2, rln_g, rln_b, Xb);
    gemm(Xb, 264, gru_Wihb, gru_bih, GIb, 768, 768, 264, 0);                   // gi
    gemm(HPb, 256, gru_Whhb, gru_bhh, GHb, 768, 768, 256, 0);                  // gh
    glue_gru<<<MROWS, 256, 0, stream>>>(GIb, GHb, hidden, Hout, XQb, Xb);
    gemm(XQb, 264, qp_Wb, nullptr, QVb, 256, 256, 264, 0);                     // q_vec
    glue_final<<<2048, 256, 0, stream>>>(QVb, Hout, enemy_feats, COMP + 33792, COMP + 41984,
                                         qn_W, qn_b, Qout);
}

// Round 2
// 764.990 us; speedup vs baseline: 1.5262x; 1.5262x over previous
//
#include <hip/hip_runtime.h>
#include <hip/hip_bf16.h>

// CAPERNN_ContRoles_HPN — round 2: deep weight composition; glue kernels do only
// softmax/means/GRU; all dense math in bf16 MFMA GEMMs.
// M = BN = 16384 rows, H=256, NH=4, HD=64, NA=15, NE=16, RD=8, NMOVE=6.

#define MROWS 16384

typedef __attribute__((ext_vector_type(8))) short short8;
typedef __attribute__((ext_vector_type(4))) float float4v;

__device__ __forceinline__ unsigned short f2b(float f) {
    __hip_bfloat16 h = __float2bfloat16(f);
    return *reinterpret_cast<unsigned short*>(&h);
}
__device__ __forceinline__ float b2f(unsigned short u) {
    __hip_bfloat16 h;
    *reinterpret_cast<unsigned short*>(&h) = u;
    return __bfloat162float(h);
}

// ---------------- prep: fp32 -> bf16 conversion ----------------
struct CvtTable {
    const float* src[8];
    unsigned short* dst[8];
    int n[8];
};
__global__ void cvt_kernel(CvtTable T) {
    int e = blockIdx.y;
    int i = (blockIdx.x * 256 + threadIdx.x) * 4;
    if (i >= T.n[e]) return;
    float4 v = *(const float4*)(T.src[e] + i);
    unsigned short* d = T.dst[e] + i;
    d[0] = f2b(v.x); d[1] = f2b(v.y); d[2] = f2b(v.z); d[3] = f2b(v.w);
}

// ---------------- generic compose ops ----------------
// type 0: matmul -> bf16 out; 1: matmul -> fp32 out; 2: copy-cvt -> bf16; 3: zero bf16
struct COp {
    int type;
    const float* A; int sAi, sAk;
    const float* B; int sBj, sBk;
    void* O; int sOi;
    int I, J, K;
    int nb, aB, bB, oB;
};
struct COpSet { int n; COp ops[18]; };

__global__ void compose_ops(COpSet S) {
    int op = blockIdx.y;
    if (op >= S.n) return;
    COp o = S.ops[op];
    int total = o.nb * o.I * o.J;
    int idx = blockIdx.x * 256 + threadIdx.x;
    if (idx >= total) return;
    int IJ = o.I * o.J;
    int b = idx / IJ;
    int rem = idx - b * IJ;
    int i = rem / o.J, j = rem - i * o.J;
    long oidx = (long)b * o.oB + (long)i * o.sOi + j;
    if (o.type == 3) { ((unsigned short*)o.O)[oidx] = 0; return; }
    if (o.type == 2) { ((unsigned short*)o.O)[oidx] = f2b(o.A[(long)b * o.aB + (long)i * o.sAi + (long)j * o.sAk]); return; }
    const float* a = o.A + (long)b * o.aB + (long)i * o.sAi;
    const float* bp = o.B + (long)b * o.bB + (long)j * o.sBj;
    float s = 0.f;
    for (int k = 0; k < o.K; k++) s += a[(long)k * o.sAk] * bp[(long)k * o.sBk];
    if (o.type == 0) ((unsigned short*)o.O)[oidx] = f2b(s);
    else ((float*)o.O)[oidx] = s;
}

// ---------------- bias composition (all small) ----------------
__global__ void bias_kernel(const float* WQKS_AE, const float* own_b,
                            const float* fuse_W1, const float* fuse_b1,
                            const float* cbA, const float* cbE,
                            const float* pool_W1, const float* pool_b1,
                            const float* gru_Wih, const float* gru_bih, const float* fuse_b2,
                            const float* qn_b,
                            float* qksb, float* fb, float* pb, float* gib, float* qwsb) {
    int idx = blockIdx.x * 256 + threadIdx.x;
    if (idx < 256) {
        float s = 0.f;
        for (int k = 0; k < 256; k++) s += WQKS_AE[idx * 256 + k] * own_b[k];
        qksb[idx] = s;
    } else if (idx < 512) {
        int i = idx - 256;
        float s = fuse_b1[i];
        for (int k = 0; k < 256; k++) s += fuse_W1[i * 768 + k] * own_b[k];
        for (int k = 0; k < 256; k++) s += fuse_W1[i * 768 + 256 + k] * cbA[k];
        for (int k = 0; k < 256; k++) s += fuse_W1[i * 768 + 512 + k] * cbE[k];
        fb[i] = s;
    } else if (idx < 640) {
        int i = idx - 512;
        float s = pool_b1[i];
        for (int k = 0; k < 256; k++) s += pool_W1[i * 768 + k] * own_b[k];
        pb[i] = s;
    } else if (idx < 1408) {
        int n = idx - 640;
        float s = gru_bih[n];
        for (int k = 0; k < 256; k++) s += gru_Wih[n * 264 + k] * fuse_b2[k];
        gib[n] = s;
    } else if (idx < 1448) {
        int t = idx - 1408;
        qwsb[t] = (t >= 33 && t < 39) ? qn_b[t - 33] : 0.f;
    }
}

// ---------------- bf16 MFMA GEMM: C[M x N] = A[M x K] @ W[N x K]^T (+bias)(+gelu) ----------------
__global__ __launch_bounds__(256, 2)
void gemm_bf16(const unsigned short* __restrict__ A, int lda,
               const unsigned short* __restrict__ W,
               const float* __restrict__ bias,
               unsigned short* __restrict__ C, int ldc,
               int N, int K, int act) {
    __shared__ __align__(16) unsigned short As[128 * 40];
    __shared__ __align__(16) unsigned short Bs[128 * 40];
    int tid = threadIdx.x;
    int m0 = blockIdx.x * 128, n0 = blockIdx.y * 128;
    int wave = tid >> 6, lane = tid & 63;
    int wm = (wave & 1) * 64, wn = (wave >> 1) * 64;
    int l16 = lane & 15, quad = lane >> 4;

    float4v acc[4][4];
#pragma unroll
    for (int i = 0; i < 4; i++)
#pragma unroll
        for (int j = 0; j < 4; j++) acc[i][j] = (float4v){0.f, 0.f, 0.f, 0.f};

    for (int k0 = 0; k0 < K; k0 += 32) {
#pragma unroll
        for (int i = 0; i < 2; i++) {
            int s = tid + i * 256;
            int rr = s >> 2;
            int sg = (s & 3) * 8;
            int k = k0 + sg;
            uint4 z = make_uint4(0u, 0u, 0u, 0u);
            uint4 va = (k < K) ? *(const uint4*)(A + (size_t)(m0 + rr) * lda + k) : z;
            *(uint4*)(&As[rr * 40 + sg]) = va;
            uint4 vb = (k < K && (n0 + rr) < N) ? *(const uint4*)(W + (size_t)(n0 + rr) * K + k) : z;
            *(uint4*)(&Bs[rr * 40 + sg]) = vb;
        }
        __syncthreads();
        short8 a[4], b[4];
#pragma unroll
        for (int i = 0; i < 4; i++) {
            a[i] = *(const short8*)(&As[(wm + i * 16 + l16) * 40 + quad * 8]);
            b[i] = *(const short8*)(&Bs[(wn + i * 16 + l16) * 40 + quad * 8]);
        }
#pragma unroll
        for (int i = 0; i < 4; i++)
#pragma unroll
            for (int j = 0; j < 4; j++)
                acc[i][j] = __builtin_amdgcn_mfma_f32_16x16x32_bf16(a[i], b[j], acc[i][j], 0, 0, 0);
        __syncthreads();
    }
#pragma unroll
    for (int i = 0; i < 4; i++) {
#pragma unroll
        for (int j = 0; j < 4; j++) {
#pragma unroll
            for (int rr = 0; rr < 4; rr++) {
                int rowm = m0 + wm + i * 16 + quad * 4 + rr;
                int coln = wn + j * 16 + l16;
                if (n0 + coln >= N) continue;
                float v = acc[i][j][rr];
                if (bias) v += bias[n0 + coln];
                if (act == 1) v = 0.5f * v * (1.f + erff(v * 0.70710678f));
                C[(size_t)rowm * ldc + n0 + coln] = f2b(v);
            }
        }
    }
}

// ---------------- LayerNorm in-place on bf16 buffer, blockDim.x == F ----------------
__global__ void ln_bf16(unsigned short* X, int ld, const float* g, const float* b, int F) {
    int row = blockIdx.x;
    int t = threadIdx.x;
    size_t idx = (size_t)row * ld + t;
    float v = b2f(X[idx]);
    float s = v, q = v * v;
    for (int o = 32; o; o >>= 1) {
        s += __shfl_xor(s, o, 64);
        q += __shfl_xor(q, o, 64);
    }
    __shared__ float rs[4], rq[4];
    int w = t >> 6, nw = F >> 6;
    if ((t & 63) == 0) { rs[w] = s; rq[w] = q; }
    __syncthreads();
    float ts = 0.f, tq = 0.f;
    for (int i = 0; i < nw; i++) { ts += rs[i]; tq += rq[i]; }
    float mean = ts / F;
    float var = tq / F - mean * mean;
    float o = (v - mean) * rsqrtf(var + 1e-5f) * g[t] + b[t];
    X[idx] = f2b(o);
}

// ---------------- attention glue: softmax + weighted feats + means (4 rows/block) ----------------
__global__ __launch_bounds__(256)
void glue_attn(const float* __restrict__ allyf, const float* __restrict__ enemyf,
               const float* __restrict__ ownf, const unsigned short* __restrict__ QKS,
               unsigned short* __restrict__ X) {
    __shared__ float af[4][495];    // 15 x 33
    __shared__ float ef[4][528];    // 16 x 33
    __shared__ float qk[4][256];
    __shared__ float attnA[4][64];
    __shared__ float attnE[4][64];
    __shared__ float mskA[4][16];
    __shared__ float mskE[4][16];
    int tid = threadIdx.x;
    size_t rb = (size_t)blockIdx.x * 4;

    for (int idx = tid; idx < 1920; idx += 256) {
        int r = idx / 480, w0 = idx % 480;
        af[r][(w0 >> 5) * 33 + (w0 & 31)] = allyf[(rb + r) * 480 + w0];
    }
    for (int idx = tid; idx < 2048; idx += 256) {
        int r = idx >> 9, w0 = idx & 511;
        ef[r][(w0 >> 5) * 33 + (w0 & 31)] = enemyf[(rb + r) * 512 + w0];
    }
    for (int idx = tid; idx < 1024; idx += 256)
        qk[idx >> 8][idx & 255] = b2f(QKS[(rb + (idx >> 8)) * 256 + (idx & 255)]);
    if (tid < 128) {
        int r = tid >> 5, c = tid & 31;
        X[(rb + r) * 360 + c] = f2b(ownf[(rb + r) * 32 + c]);
    } else if (tid < 152) {
        int r = (tid - 128) / 6, c = 98 + (tid - 128) % 6;
        X[(rb + r) * 360 + c] = 0;
    }
    __syncthreads();

    int r = tid >> 6, lane = tid & 63;
    int h = lane >> 4, m = lane & 15;
    // masks
    if (lane < 15) {
        bool nz = false;
        for (int d = 0; d < 32; d++) nz |= (af[r][lane * 33 + d] != 0.f);
        mskA[r][lane] = nz ? 1.f : 0.f;
    } else if (lane == 15) {
        mskA[r][15] = 0.f;
    } else if (lane < 32) {
        int mm = lane - 16;
        bool nz = false;
        for (int d = 0; d < 32; d++) nz |= (ef[r][mm * 33 + d] != 0.f);
        mskE[r][mm] = nz ? 1.f : 0.f;
    }
    __syncthreads();
    // scores + softmax, ally (15 entities)
    {
        float sc = -3.0e38f;
        if (m < 15) {
            float s = 0.f;
            for (int d = 0; d < 32; d++) s += qk[r][h * 32 + d] * af[r][m * 33 + d];
            sc = (mskA[r][m] > 0.f) ? s * 0.125f : -1e9f;
        }
        float mx = sc;
        for (int o = 8; o; o >>= 1) mx = fmaxf(mx, __shfl_xor(mx, o, 64));
        float e = (m < 15) ? __expf(sc - mx) : 0.f;
        float sm = e;
        for (int o = 8; o; o >>= 1) sm += __shfl_xor(sm, o, 64);
        attnA[r][h * 16 + m] = e / sm;
    }
    // scores + softmax, enemy (16 entities)
    {
        float s = 0.f;
        for (int d = 0; d < 32; d++) s += qk[r][128 + h * 32 + d] * ef[r][m * 33 + d];
        float sc = (mskE[r][m] > 0.f) ? s * 0.125f : -1e9f;
        float mx = sc;
        for (int o = 8; o; o >>= 1) mx = fmaxf(mx, __shfl_xor(mx, o, 64));
        float e = __expf(sc - mx);
        float sm = e;
        for (int o = 8; o; o >>= 1) sm += __shfl_xor(sm, o, 64);
        attnE[r][h * 16 + m] = e / sm;
    }
    __syncthreads();
    // weighted feats -> X[104..231] (A), X[232..359] (E)
    size_t row = rb + r;
#pragma unroll
    for (int it = 0; it < 2; it++) {
        int idx = lane + it * 64;
        int hh = idx >> 5, c = idx & 31;
        float sA = 0.f;
        for (int mm = 0; mm < 15; mm++) sA += attnA[r][hh * 16 + mm] * af[r][mm * 33 + c];
        X[row * 360 + 104 + idx] = f2b(sA);
        float sE = 0.f;
        for (int mm = 0; mm < 16; mm++) sE += attnE[r][hh * 16 + mm] * ef[r][mm * 33 + c];
        X[row * 360 + 232 + idx] = f2b(sE);
    }
    // masked means -> X[32..63] (mfA), X[64..95] (mfE); flags -> X[96], X[97]
    if (lane < 32) {
        float cnt = 0.f;
        for (int mm = 0; mm < 15; mm++) cnt += mskA[r][mm];
        float s = 0.f;
        for (int mm = 0; mm < 15; mm++) s += af[r][mm * 33 + lane];
        X[row * 360 + 32 + lane] = f2b(s / fmaxf(cnt, 1e-8f));
        if (lane == 0) X[row * 360 + 96] = f2b(cnt > 0.f ? 1.f : 0.f);
    } else {
        int c = lane - 32;
        float cnt = 0.f;
        for (int mm = 0; mm < 16; mm++) cnt += mskE[r][mm];
        float s = 0.f;
        for (int mm = 0; mm < 16; mm++) s += ef[r][mm * 33 + c];
        X[row * 360 + 64 + c] = f2b(s / fmaxf(cnt, 1e-8f));
        if (c == 0) X[row * 360 + 97] = f2b(cnt > 0.f ? 1.f : 0.f);
    }
}

// ---------------- role head: r = LN8(tanh(T3n @ role_W2^T + b2)) -> XG[:,256:264] ----------------
__global__ void glue_role(const unsigned short* __restrict__ T3, const float* __restrict__ W2,
                          const float* __restrict__ b2, const float* __restrict__ rg,
                          const float* __restrict__ rb, unsigned short* __restrict__ XG) {
    __shared__ float t3[32][132];
    int tid = threadIdx.x;
    size_t base = (size_t)blockIdx.x * 4096;
    for (int idx = tid; idx < 4096; idx += 256)
        t3[idx >> 7][idx & 127] = b2f(T3[base + idx]);
    __syncthreads();
    int r = tid >> 3, t = tid & 7;
    size_t row = (size_t)blockIdx.x * 32 + r;
    float s = b2[t];
    const float* w = W2 + t * 128;
    for (int d = 0; d < 128; d++) s += w[d] * t3[r][d];
    float v = tanhf(s);
    float mean = v;
    for (int o = 4; o; o >>= 1) mean += __shfl_xor(mean, o, 8);
    mean *= 0.125f;
    float dv = v - mean, q = dv * dv;
    for (int o = 4; o; o >>= 1) q += __shfl_xor(q, o, 8);
    q *= 0.125f;
    float out = dv * rsqrtf(q + 1e-5f) * rg[t] + rb[t];
    XG[row * 264 + 256 + t] = f2b(out);
}

// ---------------- GRU glue ----------------
__global__ void glue_gru(const unsigned short* __restrict__ GI, const unsigned short* __restrict__ GH,
                         const float* __restrict__ hp, float* __restrict__ hout,
                         unsigned short* __restrict__ XQ, const unsigned short* __restrict__ XG) {
    size_t row = blockIdx.x;
    int i = threadIdx.x;
    size_t b = row * 768;
    float ir = b2f(GI[b + i]), iz = b2f(GI[b + 256 + i]), in_ = b2f(GI[b + 512 + i]);
    float hr = b2f(GH[b + i]), hz = b2f(GH[b + 256 + i]), hn = b2f(GH[b + 512 + i]);
    float rg = 1.f / (1.f + __expf(-(ir + hr)));
    float zg = 1.f / (1.f + __expf(-(iz + hz)));
    float ng = tanhf(in_ + rg * hn);
    float h = (1.f - zg) * ng + zg * hp[row * 256 + i];
    hout[row * 256 + i] = h;
    XQ[row * 264 + i] = f2b(h);
    if (i < 8) XQ[row * 264 + 256 + i] = XG[row * 264 + 256 + i];
}

// ---------------- final heads ----------------
__global__ __launch_bounds__(256)
void glue_final(const unsigned short* __restrict__ QWS, const float* __restrict__ efeats,
                float* __restrict__ Q) {
    __shared__ float ef[8][528];
    __shared__ float qw[8][40];
    int tid = threadIdx.x;
    size_t rb = (size_t)blockIdx.x * 8;
    for (int idx = tid; idx < 4096; idx += 256) {
        int r = idx >> 9, w0 = idx & 511;
        ef[r][(w0 >> 5) * 33 + (w0 & 31)] = efeats[(rb + r) * 512 + w0];
    }
    for (int idx = tid; idx < 320; idx += 256) {
        int r = idx / 40, c = idx % 40;
        qw[r][c] = b2f(QWS[(rb + r) * 40 + c]);
    }
    __syncthreads();
    int r = tid >> 5, t = tid & 31;
    size_t row = rb + r;
    float lg = 0.f, mk = 0.f;
    if (t < 16) {
        const float* fr = ef[r] + t * 33;
        bool nz = false;
        float s = 0.f;
        for (int d = 0; d < 32; d++) { nz |= (fr[d] != 0.f); s += qw[r][d] * fr[d]; }
        mk = nz ? 1.f : 0.f;
        lg = (s + qw[r][32]) * 0.0625f;
    }
    float sv = mk * lg, cv = mk;
    for (int o = 8; o; o >>= 1) { sv += __shfl_xor(sv, o, 64); cv += __shfl_xor(cv, o, 64); }
    float mean = sv / fmaxf(cv, 1.f);
    if (t < 16) Q[row * 22 + 6 + t] = (mk > 0.f ? lg : -1e9f) - mean;
    if (t < 6) Q[row * 22 + t] = qw[r][33 + t];
}

// ---------------- host orchestration ----------------
extern "C" void kernel_launch(void* const* d_in, const int* in_sizes, int n_in,
                              void* d_out, int out_size, void* d_ws, size_t ws_size,
                              hipStream_t stream) {
    const float* own_feats = (const float*)d_in[1];
    const float* ally_feats = (const float*)d_in[2];
    const float* enemy_feats = (const float*)d_in[3];
    const float* hidden = (const float*)d_in[4];
    const float* own_W = (const float*)d_in[5];   const float* own_b = (const float*)d_in[6];
    const float* ally_W = (const float*)d_in[7];  const float* ally_b = (const float*)d_in[8];
    const float* en_W = (const float*)d_in[9];    const float* en_b = (const float*)d_in[10];
    const float* aA_Wq = (const float*)d_in[11];  const float* aA_Wk = (const float*)d_in[12];
    const float* aA_Wv = (const float*)d_in[13];  const float* aA_Wo = (const float*)d_in[14];
    const float* aE_Wq = (const float*)d_in[15];  const float* aE_Wk = (const float*)d_in[16];
    const float* aE_Wv = (const float*)d_in[17];  const float* aE_Wo = (const float*)d_in[18];
    const float* fuse_W1 = (const float*)d_in[19]; const float* fuse_b1 = (const float*)d_in[20];
    const float* fuse_g1 = (const float*)d_in[21]; const float* fuse_be1 = (const float*)d_in[22];
    const float* fuse_W2 = (const float*)d_in[23]; const float* fuse_b2 = (const float*)d_in[24];
    const float* pool_W1 = (const float*)d_in[25]; const float* pool_b1 = (const float*)d_in[26];
    const float* pool_g1 = (const float*)d_in[27]; const float* pool_be1 = (const float*)d_in[28];
    const float* pool_W2 = (const float*)d_in[29]; const float* pool_b2 = (const float*)d_in[30];
    const float* role_W1 = (const float*)d_in[31]; const float* role_b1 = (const float*)d_in[32];
    const float* role_g1 = (const float*)d_in[33]; const float* role_be1 = (const float*)d_in[34];
    const float* role_W2 = (const float*)d_in[35]; const float* role_b2 = (const float*)d_in[36];
    const float* rln_g = (const float*)d_in[37];   const float* rln_b = (const float*)d_in[38];
    const float* gru_Wih = (const float*)d_in[39]; const float* gru_Whh = (const float*)d_in[40];
    const float* gru_bih = (const float*)d_in[41]; const float* gru_bhh = (const float*)d_in[42];
    const float* qn_W = (const float*)d_in[43];    const float* qn_b = (const float*)d_in[44];
    const float* qp_W = (const float*)d_in[45];    const float* kp_W = (const float*)d_in[46];

    char* wsp = (char*)d_ws;
    size_t off = 0;
    auto alloc = [&](size_t bytes) { void* p = wsp + off; off = (off + bytes + 255) & ~(size_t)255; return p; };

    unsigned short* X    = (unsigned short*)alloc((size_t)MROWS * 360 * 2);
    unsigned short* XG   = (unsigned short*)alloc((size_t)MROWS * 264 * 2);
    unsigned short* GIb  = (unsigned short*)alloc((size_t)MROWS * 768 * 2);
    unsigned short* GHb  = (unsigned short*)alloc((size_t)MROWS * 768 * 2);
    unsigned short* XQ   = (unsigned short*)alloc((size_t)MROWS * 264 * 2);
    unsigned short* QKSb = (unsigned short*)alloc((size_t)MROWS * 256 * 2);
    unsigned short* HPb  = (unsigned short*)alloc((size_t)MROWS * 256 * 2);
    unsigned short* T2b  = (unsigned short*)alloc((size_t)MROWS * 128 * 2);
    unsigned short* POOLb= (unsigned short*)alloc((size_t)MROWS * 128 * 2);
    unsigned short* T3b  = (unsigned short*)alloc((size_t)MROWS * 128 * 2);
    unsigned short* QWSb = (unsigned short*)alloc((size_t)MROWS * 40 * 2);
    unsigned short* OWNb = (unsigned short*)alloc((size_t)MROWS * 32 * 2);
    // composed bf16 weights
    unsigned short* WQKSO = (unsigned short*)alloc(256 * 32 * 2);
    unsigned short* FW    = (unsigned short*)alloc(256 * 360 * 2);
    unsigned short* PW    = (unsigned short*)alloc(128 * 104 * 2);
    unsigned short* GIW   = (unsigned short*)alloc(768 * 264 * 2);
    unsigned short* QWSW  = (unsigned short*)alloc(40 * 264 * 2);
    unsigned short* Whhb  = (unsigned short*)alloc(768 * 256 * 2);
    unsigned short* pW2b  = (unsigned short*)alloc(128 * 128 * 2);
    unsigned short* rW1b  = (unsigned short*)alloc(128 * 128 * 2);
    // fp32 scratch
    float* WkAp = (float*)alloc(256 * 32 * 4);
    float* WvAp = (float*)alloc(256 * 32 * 4);
    float* WkEp = (float*)alloc(256 * 32 * 4);
    float* WvEp = (float*)alloc(256 * 32 * 4);
    float* Wkpp = (float*)alloc(256 * 32 * 4);
    float* bvAp = (float*)alloc(256 * 4);
    float* bvEp = (float*)alloc(256 * 4);
    float* bkpp = (float*)alloc(256 * 4);
    float* WQKS_AE = (float*)alloc(256 * 256 * 4);
    float* WoVA = (float*)alloc(256 * 128 * 4);
    float* WoVE = (float*)alloc(256 * 128 * 4);
    float* cbA = (float*)alloc(256 * 4);
    float* cbE = (float*)alloc(256 * 4);
    float* qksb = (float*)alloc(256 * 4);
    float* fb   = (float*)alloc(256 * 4);
    float* pb   = (float*)alloc(128 * 4);
    float* gib  = (float*)alloc(768 * 4);
    float* qwsb = (float*)alloc(40 * 4);

    float* Qout = (float*)d_out;
    float* Hout = Qout + (size_t)MROWS * 22;

    // ---- cvt (bf16 copies) ----
    CvtTable ct;
    {
        int i = 0;
        auto add = [&](const float* s, unsigned short* d, int n) { ct.src[i] = s; ct.dst[i] = d; ct.n[i] = n; i++; };
        add(own_feats, OWNb, MROWS * 32);
        add(hidden, HPb, MROWS * 256);
        add(gru_Whh, Whhb, 768 * 256);
        add(pool_W2, pW2b, 128 * 128);
        add(role_W1, rW1b, 128 * 128);
        cvt_kernel<<<dim3(4096, 5), 256, 0, stream>>>(ct);
    }

    // ---- compose stage 1 ----
    {
        COpSet S; S.n = 8;
        auto mm = [&](int t, const float* A, int sAi, int sAk, const float* B, int sBj, int sBk,
                      void* O, int sOi, int I, int J, int K, int nb = 1, int aB = 0, int bB = 0, int oB = 0) {
            return COp{t, A, sAi, sAk, B, sBj, sBk, O, sOi, I, J, K, nb, aB, bB, oB};
        };
        S.ops[0] = mm(1, aA_Wk, 256, 1, ally_W, 1, 32, WkAp, 32, 256, 32, 256);
        S.ops[1] = mm(1, aA_Wv, 256, 1, ally_W, 1, 32, WvAp, 32, 256, 32, 256);
        S.ops[2] = mm(1, aE_Wk, 256, 1, en_W, 1, 32, WkEp, 32, 256, 32, 256);
        S.ops[3] = mm(1, aE_Wv, 256, 1, en_W, 1, 32, WvEp, 32, 256, 32, 256);
        S.ops[4] = mm(1, kp_W, 256, 1, en_W, 1, 32, Wkpp, 32, 256, 32, 256);
        S.ops[5] = mm(1, aA_Wv, 256, 1, ally_b, 0, 1, bvAp, 1, 256, 1, 256);
        S.ops[6] = mm(1, aE_Wv, 256, 1, en_b, 0, 1, bvEp, 1, 256, 1, 256);
        S.ops[7] = mm(1, kp_W, 256, 1, en_b, 0, 1, bkpp, 1, 256, 1, 256);
        compose_ops<<<dim3(32, 8), 256, 0, stream>>>(S);
    }
    // ---- compose stage 2 ----
    {
        COpSet S; S.n = 6;
        S.ops[0] = COp{1, WkAp, 1, 32, aA_Wq, 1, 256, WQKS_AE, 256, 32, 256, 64, 4, 2048, 16384, 8192};
        S.ops[1] = COp{1, WkEp, 1, 32, aE_Wq, 1, 256, WQKS_AE + 128 * 256, 256, 32, 256, 64, 4, 2048, 16384, 8192};
        S.ops[2] = COp{1, aA_Wo, 256, 1, WvAp, 1, 32, WoVA, 128, 256, 32, 64, 4, 64, 2048, 32};
        S.ops[3] = COp{1, aE_Wo, 256, 1, WvEp, 1, 32, WoVE, 128, 256, 32, 64, 4, 64, 2048, 32};
        S.ops[4] = COp{1, aA_Wo, 256, 1, bvAp, 0, 1, cbA, 1, 256, 1, 256, 1, 0, 0, 0};
        S.ops[5] = COp{1, aE_Wo, 256, 1, bvEp, 0, 1, cbE, 1, 256, 1, 256, 1, 0, 0, 0};
        compose_ops<<<dim3(128, 6), 256, 0, stream>>>(S);
    }
    // ---- biases ----
    bias_kernel<<<6, 256, 0, stream>>>(WQKS_AE, own_b, fuse_W1, fuse_b1, cbA, cbE,
                                       pool_W1, pool_b1, gru_Wih, gru_bih, fuse_b2,
                                       qn_b, qksb, fb, pb, gib, qwsb);
    // ---- compose stage 3 (final bf16 weights) ----
    {
        COpSet S; S.n = 18;
        S.ops[0]  = COp{0, WQKS_AE, 256, 1, own_W, 1, 32, WQKSO, 32, 256, 32, 256, 1, 0, 0, 0};
        S.ops[1]  = COp{0, fuse_W1, 768, 1, own_W, 1, 32, FW, 360, 256, 32, 256, 1, 0, 0, 0};
        S.ops[2]  = COp{3, nullptr, 0, 0, nullptr, 0, 0, FW + 32, 360, 256, 72, 0, 1, 0, 0, 0};
        S.ops[3]  = COp{0, fuse_W1 + 256, 768, 1, WoVA, 1, 128, FW + 104, 360, 256, 128, 256, 1, 0, 0, 0};
        S.ops[4]  = COp{0, fuse_W1 + 512, 768, 1, WoVE, 1, 128, FW + 232, 360, 256, 128, 256, 1, 0, 0, 0};
        S.ops[5]  = COp{0, pool_W1, 768, 1, own_W, 1, 32, PW, 104, 128, 32, 256, 1, 0, 0, 0};
        S.ops[6]  = COp{0, pool_W1 + 256, 768, 1, ally_W, 1, 32, PW + 32, 104, 128, 32, 256, 1, 0, 0, 0};
        S.ops[7]  = COp{0, pool_W1 + 512, 768, 1, en_W, 1, 32, PW + 64, 104, 128, 32, 256, 1, 0, 0, 0};
        S.ops[8]  = COp{0, pool_W1 + 256, 768, 1, ally_b, 0, 1, PW + 96, 104, 128, 1, 256, 1, 0, 0, 0};
        S.ops[9]  = COp{0, pool_W1 + 512, 768, 1, en_b, 0, 1, PW + 97, 104, 128, 1, 256, 1, 0, 0, 0};
        S.ops[10] = COp{3, nullptr, 0, 0, nullptr, 0, 0, PW + 98, 104, 128, 6, 0, 1, 0, 0, 0};
        S.ops[11] = COp{0, gru_Wih, 264, 1, fuse_W2, 1, 256, GIW, 264, 768, 256, 256, 1, 0, 0, 0};
        S.ops[12] = COp{2, gru_Wih + 256, 264, 1, nullptr, 0, 0, GIW + 256, 264, 768, 8, 0, 1, 0, 0, 0};
        S.ops[13] = COp{0, Wkpp, 1, 32, qp_W, 1, 264, QWSW, 264, 32, 264, 256, 1, 0, 0, 0};
        S.ops[14] = COp{0, bkpp, 0, 1, qp_W, 1, 264, QWSW + 32 * 264, 264, 1, 264, 256, 1, 0, 0, 0};
        S.ops[15] = COp{2, qn_W, 256, 1, nullptr, 0, 0, QWSW + 33 * 264, 264, 6, 256, 0, 1, 0, 0, 0};
        S.ops[16] = COp{3, nullptr, 0, 0, nullptr, 0, 0, QWSW + 33 * 264 + 256, 264, 6, 8, 0, 1, 0, 0, 0};
        S.ops[17] = COp{3, nullptr, 0, 0, nullptr, 0, 0, QWSW + 39 * 264, 264, 1, 264, 0, 1, 0, 0, 0};
        compose_ops<<<dim3(768, 18), 256, 0, stream>>>(S);
    }

    auto gemm = [&](const unsigned short* A, int lda, const unsigned short* Wm, const float* bias,
                    unsigned short* C, int ldc, int N, int K, int act) {
        gemm_bf16<<<dim3(MROWS / 128, (N + 127) / 128), 256, 0, stream>>>(A, lda, Wm, bias, C, ldc, N, K, act);
    };

    gemm(OWNb, 32, WQKSO, qksb, QKSb, 256, 256, 32, 0);                         // QKS
    glue_attn<<<MROWS / 4, 256, 0, stream>>>(ally_feats, enemy_feats, own_feats, QKSb, X);
    gemm(X, 360, FW, fb, XG, 264, 256, 360, 1);                                 // fuse1 + gelu
    ln_bf16<<<MROWS, 256, 0, stream>>>(XG, 264, fuse_g1, fuse_be1, 256);
    gemm(X, 360, PW, pb, T2b, 128, 128, 104, 1);                                // pool1 + gelu
    ln_bf16<<<MROWS, 128, 0, stream>>>(T2b, 128, pool_g1, pool_be1, 128);
    gemm(T2b, 128, pW2b, pool_b2, POOLb, 128, 128, 128, 0);                     // pooled
    gemm(POOLb, 128, rW1b, role_b1, T3b, 128, 128, 128, 1);                     // role1 + gelu
    ln_bf16<<<MROWS, 128, 0, stream>>>(T3b, 128, role_g1, role_be1, 128);
    glue_role<<<MROWS / 32, 256, 0, stream>>>(T3b, role_W2, role_b2, rln_g, rln_b, XG);
    gemm(XG, 264, GIW, gib, GIb, 768, 768, 264, 0);                             // gi (fuse_W2 folded)
    gemm(HPb, 256, Whhb, gru_bhh, GHb, 768, 768, 256, 0);                       // gh
    glue_gru<<<MROWS, 256, 0, stream>>>(GIb, GHb, hidden, Hout, XQ, XG);
    gemm(XQ, 264, QWSW, qwsb, QWSb, 40, 40, 264, 0);                            // qws + c0 + q_normal
    glue_final<<<MROWS / 8, 256, 0, stream>>>(QWSb, enemy_feats, Qout);
}

// Round 3
// 591.186 us; speedup vs baseline: 1.9749x; 1.2940x over previous
//
#include <hip/hip_runtime.h>
#include <hip/hip_bf16.h>

// CAPERNN_ContRoles_HPN — round 3: tiled compose kernels, QKS folded into glue_attn,
// pool_W2∘role_W1 composed, GRU as RZ/IN/HN gemms over [XG | h_prev].
// M = BN = 16384, H=256, NH=4, HD=64, NA=15, NE=16, RD=8, NMOVE=6.

#define MROWS 16384

typedef __attribute__((ext_vector_type(8))) short short8;
typedef __attribute__((ext_vector_type(4))) float float4v;

__device__ __forceinline__ unsigned short f2b(float f) {
    __hip_bfloat16 h = __float2bfloat16(f);
    return *reinterpret_cast<unsigned short*>(&h);
}
__device__ __forceinline__ float b2f(unsigned short u) {
    __hip_bfloat16 h;
    *reinterpret_cast<unsigned short*>(&h) = u;
    return __bfloat162float(h);
}

// ---------------- hidden -> XG cols 264..520 (bf16) ----------------
__global__ void cvt_hidden(const float* __restrict__ hp, unsigned short* __restrict__ XG) {
    int idx = blockIdx.x * 256 + threadIdx.x;   // one per 4 elems
    int row = idx >> 6, c4 = (idx & 63) * 4;
    float4 v = *(const float4*)(hp + (size_t)row * 256 + c4);
    unsigned short* d = XG + (size_t)row * 520 + 264 + c4;
    d[0] = f2b(v.x); d[1] = f2b(v.y); d[2] = f2b(v.z); d[3] = f2b(v.w);
}

// ---------------- tiled compose: 32x32 output tiles, LDS-staged ----------------
// type 0: matmul->bf16, 1: matmul->fp32, 2: cvt copy->bf16, 3: zero bf16
struct TOp {
    int type;
    const float* A; int sAi, sAk;
    const float* B; int sBj, sBk;
    void* O; int sOi;
    int I, J, K;
    int nb; int aB, bB, oB;
};
struct TOpSet { int n; int tiles[24]; TOp ops[24]; };

__global__ __launch_bounds__(256)
void compose_tiled(TOpSet S) {
    int t = blockIdx.x;
    int op = 0;
    while (op < S.n && t >= S.tiles[op]) { t -= S.tiles[op]; op++; }
    if (op >= S.n) return;
    TOp o = S.ops[op];
    int ti = (o.I + 31) >> 5, tj = (o.J + 31) >> 5;
    int per = ti * tj;
    int b = t / per;
    int rem = t - b * per;
    int i0 = (rem / tj) * 32, j0 = (rem % tj) * 32;
    int tid = threadIdx.x;
    if (o.type >= 2) {
        for (int e = tid; e < 1024; e += 256) {
            int r = e >> 5, c = e & 31;
            int i = i0 + r, j = j0 + c;
            if (i < o.I && j < o.J) {
                unsigned short v = 0;
                if (o.type == 2) v = f2b(o.A[(long)b * o.aB + (long)i * o.sAi + (long)j * o.sAk]);
                ((unsigned short*)o.O)[(long)b * o.oB + (long)i * o.sOi + j] = v;
            }
        }
        return;
    }
    __shared__ float As[32][33];
    __shared__ float Bs[32][33];
    int tx = tid & 15, ty = tid >> 4;
    float a00 = 0.f, a01 = 0.f, a10 = 0.f, a11 = 0.f;
    const float* Ab = o.A + (long)b * o.aB;
    const float* Bb = o.B + (long)b * o.bB;
    for (int k0 = 0; k0 < o.K; k0 += 32) {
        for (int e = tid; e < 1024; e += 256) {
            int r = e >> 5, c = e & 31;
            As[r][c] = (i0 + r < o.I && k0 + c < o.K)
                       ? Ab[(long)(i0 + r) * o.sAi + (long)(k0 + c) * o.sAk] : 0.f;
            Bs[r][c] = (k0 + r < o.K && j0 + c < o.J)
                       ? Bb[(long)(j0 + c) * o.sBj + (long)(k0 + r) * o.sBk] : 0.f;
        }
        __syncthreads();
#pragma unroll
        for (int k = 0; k < 32; k++) {
            float x0 = As[ty * 2][k], x1 = As[ty * 2 + 1][k];
            float y0 = Bs[k][tx * 2], y1 = Bs[k][tx * 2 + 1];
            a00 += x0 * y0; a01 += x0 * y1; a10 += x1 * y0; a11 += x1 * y1;
        }
        __syncthreads();
    }
    int i = i0 + ty * 2, j = j0 + tx * 2;
    float vals[2][2] = {{a00, a01}, {a10, a11}};
#pragma unroll
    for (int di = 0; di < 2; di++)
#pragma unroll
        for (int dj = 0; dj < 2; dj++) {
            int ii = i + di, jj = j + dj;
            if (ii < o.I && jj < o.J) {
                long oidx = (long)b * o.oB + (long)ii * o.sOi + jj;
                if (o.type == 0) ((unsigned short*)o.O)[oidx] = f2b(vals[di][dj]);
                else ((float*)o.O)[oidx] = vals[di][dj];
            }
        }
}

// ---------------- matvec ops: one wave per output ----------------
struct MOp { const float* A; int sAi; const float* x; const float* b1; const float* b2; float* out; int I, K; };
struct MOpSet { int n; int waves[10]; MOp ops[10]; };

__global__ void mv_ops(MOpSet S) {
    int wid = blockIdx.x * 4 + (threadIdx.x >> 6);
    int lane = threadIdx.x & 63;
    int op = 0;
    while (op < S.n && wid >= S.waves[op]) { wid -= S.waves[op]; op++; }
    if (op >= S.n) return;
    MOp o = S.ops[op];
    float s = 0.f;
    for (int k = lane; k < o.K; k += 64) s += o.A[(long)wid * o.sAi + k] * o.x[k];
    for (int off = 32; off; off >>= 1) s += __shfl_xor(s, off, 64);
    if (lane == 0) {
        if (o.b1) s += o.b1[wid];
        if (o.b2) s += o.b2[wid];
        o.out[wid] = s;
    }
}

// ---------------- bf16 MFMA GEMM: C[MxN] = A[MxK] @ W[NxK]^T (+bias)(+gelu) ----------------
__global__ __launch_bounds__(256, 2)
void gemm_bf16(const unsigned short* __restrict__ A, int lda,
               const unsigned short* __restrict__ W,
               const float* __restrict__ bias,
               unsigned short* __restrict__ C, int ldc,
               int N, int K, int act) {
    __shared__ __align__(16) unsigned short As[128 * 40];
    __shared__ __align__(16) unsigned short Bs[128 * 40];
    int tid = threadIdx.x;
    int m0 = blockIdx.x * 128, n0 = blockIdx.y * 128;
    int wave = tid >> 6, lane = tid & 63;
    int wm = (wave & 1) * 64, wn = (wave >> 1) * 64;
    int l16 = lane & 15, quad = lane >> 4;

    float4v acc[4][4];
#pragma unroll
    for (int i = 0; i < 4; i++)
#pragma unroll
        for (int j = 0; j < 4; j++) acc[i][j] = (float4v){0.f, 0.f, 0.f, 0.f};

    for (int k0 = 0; k0 < K; k0 += 32) {
#pragma unroll
        for (int i = 0; i < 2; i++) {
            int s = tid + i * 256;
            int rr = s >> 2;
            int sg = (s & 3) * 8;
            int k = k0 + sg;
            uint4 z = make_uint4(0u, 0u, 0u, 0u);
            uint4 va = (k < K) ? *(const uint4*)(A + (size_t)(m0 + rr) * lda + k) : z;
            *(uint4*)(&As[rr * 40 + sg]) = va;
            uint4 vb = (k < K && (n0 + rr) < N) ? *(const uint4*)(W + (size_t)(n0 + rr) * K + k) : z;
            *(uint4*)(&Bs[rr * 40 + sg]) = vb;
        }
        __syncthreads();
        short8 a[4], b[4];
#pragma unroll
        for (int i = 0; i < 4; i++) {
            a[i] = *(const short8*)(&As[(wm + i * 16 + l16) * 40 + quad * 8]);
            b[i] = *(const short8*)(&Bs[(wn + i * 16 + l16) * 40 + quad * 8]);
        }
#pragma unroll
        for (int i = 0; i < 4; i++)
#pragma unroll
            for (int j = 0; j < 4; j++)
                acc[i][j] = __builtin_amdgcn_mfma_f32_16x16x32_bf16(a[i], b[j], acc[i][j], 0, 0, 0);
        __syncthreads();
    }
#pragma unroll
    for (int i = 0; i < 4; i++) {
#pragma unroll
        for (int j = 0; j < 4; j++) {
#pragma unroll
            for (int rr = 0; rr < 4; rr++) {
                int rowm = m0 + wm + i * 16 + quad * 4 + rr;
                int coln = wn + j * 16 + l16;
                if (n0 + coln >= N) continue;
                float v = acc[i][j][rr];
                if (bias) v += bias[n0 + coln];
                if (act == 1) v = 0.5f * v * (1.f + erff(v * 0.70710678f));
                C[(size_t)rowm * ldc + n0 + coln] = f2b(v);
            }
        }
    }
}

// ---------------- combined LN: FPC[:,0:256]->XG(ld520), FPC[:,256:384]->T2 ----------------
__global__ void ln_fp(const unsigned short* __restrict__ FPC,
                      const float* __restrict__ g1, const float* __restrict__ be1,
                      const float* __restrict__ g2, const float* __restrict__ be2,
                      unsigned short* __restrict__ XG, unsigned short* __restrict__ T2) {
    int row = blockIdx.x, t = threadIdx.x;
    float v = b2f(FPC[(size_t)row * 384 + t]);
    float s = v, q = v * v;
    for (int o = 32; o; o >>= 1) { s += __shfl_xor(s, o, 64); q += __shfl_xor(q, o, 64); }
    __shared__ float rs[6], rq[6];
    int w = t >> 6;
    if ((t & 63) == 0) { rs[w] = s; rq[w] = q; }
    __syncthreads();
    if (t < 256) {
        float ts = rs[0] + rs[1] + rs[2] + rs[3], tq = rq[0] + rq[1] + rq[2] + rq[3];
        float mean = ts * (1.f / 256.f);
        float var = tq * (1.f / 256.f) - mean * mean;
        float o = (v - mean) * rsqrtf(var + 1e-5f) * g1[t] + be1[t];
        XG[(size_t)row * 520 + t] = f2b(o);
    } else {
        int tt = t - 256;
        float ts = rs[4] + rs[5], tq = rq[4] + rq[5];
        float mean = ts * (1.f / 128.f);
        float var = tq * (1.f / 128.f) - mean * mean;
        float o = (v - mean) * rsqrtf(var + 1e-5f) * g2[tt] + be2[tt];
        T2[(size_t)row * 128 + tt] = f2b(o);
    }
}

// ---------------- LayerNorm in-place, blockDim.x == F ----------------
__global__ void ln_bf16(unsigned short* X, int ld, const float* g, const float* b, int F) {
    int row = blockIdx.x;
    int t = threadIdx.x;
    size_t idx = (size_t)row * ld + t;
    float v = b2f(X[idx]);
    float s = v, q = v * v;
    for (int o = 32; o; o >>= 1) { s += __shfl_xor(s, o, 64); q += __shfl_xor(q, o, 64); }
    __shared__ float rs[4], rq[4];
    int w = t >> 6, nw = F >> 6;
    if ((t & 63) == 0) { rs[w] = s; rq[w] = q; }
    __syncthreads();
    float ts = 0.f, tq = 0.f;
    for (int i = 0; i < nw; i++) { ts += rs[i]; tq += rq[i]; }
    float mean = ts / F;
    float var = tq / F - mean * mean;
    float o = (v - mean) * rsqrtf(var + 1e-5f) * g[t] + b[t];
    X[idx] = f2b(o);
}

// ---------------- attention glue: qk matvec + softmax + weighted feats + means ----------------
__global__ __launch_bounds__(256)
void glue_attn(const float* __restrict__ allyf, const float* __restrict__ enemyf,
               const float* __restrict__ ownf, const float* __restrict__ Wqk_g,
               const float* __restrict__ qksb, unsigned short* __restrict__ X) {
    __shared__ float af[4][495];    // 15 x 33
    __shared__ float ef[4][528];    // 16 x 33
    __shared__ float ownL[4][32];
    __shared__ float Wqk[256 * 33];
    __shared__ float qk[4][256];
    __shared__ float attnA[4][64];
    __shared__ float attnE[4][64];
    __shared__ float mskA[4][16];
    __shared__ float mskE[4][16];
    int tid = threadIdx.x;
    size_t rb = (size_t)blockIdx.x * 4;

    for (int idx = tid; idx < 1920; idx += 256) {
        int r = idx / 480, w0 = idx % 480;
        af[r][(w0 >> 5) * 33 + (w0 & 31)] = allyf[(rb + r) * 480 + w0];
    }
    for (int idx = tid; idx < 2048; idx += 256) {
        int r = idx >> 9, w0 = idx & 511;
        ef[r][(w0 >> 5) * 33 + (w0 & 31)] = enemyf[(rb + r) * 512 + w0];
    }
    for (int e = tid; e < 8192; e += 256)
        Wqk[(e >> 5) * 33 + (e & 31)] = Wqk_g[e];
    if (tid < 128) {
        int r = tid >> 5, c = tid & 31;
        float v = ownf[(rb + r) * 32 + c];
        ownL[r][c] = v;
        X[(rb + r) * 360 + c] = f2b(v);
    } else if (tid < 152) {
        int r = (tid - 128) / 6, c = 98 + (tid - 128) % 6;
        X[(rb + r) * 360 + c] = 0;
    }
    __syncthreads();

    // qk[r][i] = qksb[i] + sum_d Wqk[i][d] * own[r][d]
    {
        int i = tid;
        float base = qksb[i];
        float v0 = 0.f, v1 = 0.f, v2 = 0.f, v3 = 0.f;
#pragma unroll
        for (int d = 0; d < 32; d++) {
            float w0 = Wqk[i * 33 + d];
            v0 += w0 * ownL[0][d]; v1 += w0 * ownL[1][d];
            v2 += w0 * ownL[2][d]; v3 += w0 * ownL[3][d];
        }
        qk[0][i] = v0 + base; qk[1][i] = v1 + base;
        qk[2][i] = v2 + base; qk[3][i] = v3 + base;
    }
    // masks
    {
        int r = tid >> 6, lane = tid & 63;
        if (lane < 15) {
            bool nz = false;
            for (int d = 0; d < 32; d++) nz |= (af[r][lane * 33 + d] != 0.f);
            mskA[r][lane] = nz ? 1.f : 0.f;
        } else if (lane == 15) {
            mskA[r][15] = 0.f;
        } else if (lane < 32) {
            int mm = lane - 16;
            bool nz = false;
            for (int d = 0; d < 32; d++) nz |= (ef[r][mm * 33 + d] != 0.f);
            mskE[r][mm] = nz ? 1.f : 0.f;
        }
    }
    __syncthreads();

    int r = tid >> 6, lane = tid & 63;
    int h = lane >> 4, m = lane & 15;
    // ally softmax (15 entities)
    {
        float sc = -3.0e38f;
        if (m < 15) {
            float s = 0.f;
            for (int d = 0; d < 32; d++) s += qk[r][h * 32 + d] * af[r][m * 33 + d];
            sc = (mskA[r][m] > 0.f) ? s * 0.125f : -1e9f;
        }
        float mx = sc;
        for (int o = 8; o; o >>= 1) mx = fmaxf(mx, __shfl_xor(mx, o, 64));
        float e = (m < 15) ? __expf(sc - mx) : 0.f;
        float sm = e;
        for (int o = 8; o; o >>= 1) sm += __shfl_xor(sm, o, 64);
        attnA[r][h * 16 + m] = e / sm;
    }
    // enemy softmax (16 entities)
    {
        float s = 0.f;
        for (int d = 0; d < 32; d++) s += qk[r][128 + h * 32 + d] * ef[r][m * 33 + d];
        float sc = (mskE[r][m] > 0.f) ? s * 0.125f : -1e9f;
        float mx = sc;
        for (int o = 8; o; o >>= 1) mx = fmaxf(mx, __shfl_xor(mx, o, 64));
        float e = __expf(sc - mx);
        float sm = e;
        for (int o = 8; o; o >>= 1) sm += __shfl_xor(sm, o, 64);
        attnE[r][h * 16 + m] = e / sm;
    }
    __syncthreads();
    size_t row = rb + r;
#pragma unroll
    for (int it = 0; it < 2; it++) {
        int idx = lane + it * 64;
        int hh = idx >> 5, c = idx & 31;
        float sA = 0.f;
        for (int mm = 0; mm < 15; mm++) sA += attnA[r][hh * 16 + mm] * af[r][mm * 33 + c];
        X[row * 360 + 104 + idx] = f2b(sA);
        float sE = 0.f;
        for (int mm = 0; mm < 16; mm++) sE += attnE[r][hh * 16 + mm] * ef[r][mm * 33 + c];
        X[row * 360 + 232 + idx] = f2b(sE);
    }
    if (lane < 32) {
        float cnt = 0.f;
        for (int mm = 0; mm < 15; mm++) cnt += mskA[r][mm];
        float s = 0.f;
        for (int mm = 0; mm < 15; mm++) s += af[r][mm * 33 + lane];
        X[row * 360 + 32 + lane] = f2b(s / fmaxf(cnt, 1e-8f));
        if (lane == 0) X[row * 360 + 96] = f2b(cnt > 0.f ? 1.f : 0.f);
    } else {
        int c = lane - 32;
        float cnt = 0.f;
        for (int mm = 0; mm < 16; mm++) cnt += mskE[r][mm];
        float s = 0.f;
        for (int mm = 0; mm < 16; mm++) s += ef[r][mm * 33 + c];
        X[row * 360 + 64 + c] = f2b(s / fmaxf(cnt, 1e-8f));
        if (c == 0) X[row * 360 + 97] = f2b(cnt > 0.f ? 1.f : 0.f);
    }
}

// ---------------- role head: r = LN8(tanh(T3 @ role_W2^T + b2)) -> XG cols 256..264 ----------------
__global__ void glue_role(const unsigned short* __restrict__ T3, const float* __restrict__ W2,
                          const float* __restrict__ b2, const float* __restrict__ rg,
                          const float* __restrict__ rb, unsigned short* __restrict__ XG) {
    __shared__ float t3[32][132];
    int tid = threadIdx.x;
    size_t base = (size_t)blockIdx.x * 4096;
    for (int idx = tid; idx < 4096; idx += 256)
        t3[idx >> 7][idx & 127] = b2f(T3[base + idx]);
    __syncthreads();
    int r = tid >> 3, t = tid & 7;
    size_t row = (size_t)blockIdx.x * 32 + r;
    float s = b2[t];
    const float* w = W2 + t * 128;
    for (int d = 0; d < 128; d++) s += w[d] * t3[r][d];
    float v = tanhf(s);
    float mean = v;
    for (int o = 4; o; o >>= 1) mean += __shfl_xor(mean, o, 8);
    mean *= 0.125f;
    float dv = v - mean, q = dv * dv;
    for (int o = 4; o; o >>= 1) q += __shfl_xor(q, o, 8);
    q *= 0.125f;
    float out = dv * rsqrtf(q + 1e-5f) * rg[t] + rb[t];
    XG[row * 520 + 256 + t] = f2b(out);
}

// ---------------- GRU glue (G cols: 0..256 r-sum, 256..512 z-sum, 512..768 i_n, 768..1024 h_n) ----
__global__ void glue_gru(const unsigned short* __restrict__ G, const float* __restrict__ hp,
                         float* __restrict__ hout, unsigned short* __restrict__ XQ,
                         const unsigned short* __restrict__ XG) {
    size_t row = blockIdx.x;
    int i = threadIdx.x;
    size_t b = row * 1024;
    float rg = 1.f / (1.f + __expf(-b2f(G[b + i])));
    float zg = 1.f / (1.f + __expf(-b2f(G[b + 256 + i])));
    float ng = tanhf(b2f(G[b + 512 + i]) + rg * b2f(G[b + 768 + i]));
    float h = (1.f - zg) * ng + zg * hp[row * 256 + i];
    hout[row * 256 + i] = h;
    XQ[row * 264 + i] = f2b(h);
    if (i < 8) XQ[row * 264 + 256 + i] = XG[row * 520 + 256 + i];
}

// ---------------- final heads ----------------
__global__ __launch_bounds__(256)
void glue_final(const unsigned short* __restrict__ QWS, const float* __restrict__ efeats,
                const float* __restrict__ qnb, float* __restrict__ Q) {
    __shared__ float ef[8][528];
    __shared__ float qw[8][40];
    int tid = threadIdx.x;
    size_t rb = (size_t)blockIdx.x * 8;
    for (int idx = tid; idx < 4096; idx += 256) {
        int r = idx >> 9, w0 = idx & 511;
        ef[r][(w0 >> 5) * 33 + (w0 & 31)] = efeats[(rb + r) * 512 + w0];
    }
    for (int idx = tid; idx < 320; idx += 256) {
        int r = idx / 40, c = idx % 40;
        qw[r][c] = b2f(QWS[(rb + r) * 40 + c]);
    }
    __syncthreads();
    int r = tid >> 5, t = tid & 31;
    size_t row = rb + r;
    float lg = 0.f, mk = 0.f;
    if (t < 16) {
        const float* fr = ef[r] + t * 33;
        bool nz = false;
        float s = 0.f;
        for (int d = 0; d < 32; d++) { nz |= (fr[d] != 0.f); s += qw[r][d] * fr[d]; }
        mk = nz ? 1.f : 0.f;
        lg = (s + qw[r][32]) * 0.0625f;
    }
    float sv = mk * lg, cv = mk;
    for (int o = 8; o; o >>= 1) { sv += __shfl_xor(sv, o, 64); cv += __shfl_xor(cv, o, 64); }
    float mean = sv / fmaxf(cv, 1.f);
    if (t < 16) Q[row * 22 + 6 + t] = (mk > 0.f ? lg : -1e9f) - mean;
    if (t < 6) Q[row * 22 + t] = qw[r][33 + t] + qnb[t];
}

// ---------------- host orchestration ----------------
extern "C" void kernel_launch(void* const* d_in, const int* in_sizes, int n_in,
                              void* d_out, int out_size, void* d_ws, size_t ws_size,
                              hipStream_t stream) {
    const float* own_feats = (const float*)d_in[1];
    const float* ally_feats = (const float*)d_in[2];
    const float* enemy_feats = (const float*)d_in[3];
    const float* hidden = (const float*)d_in[4];
    const float* own_W = (const float*)d_in[5];   const float* own_b = (const float*)d_in[6];
    const float* ally_W = (const float*)d_in[7];  const float* ally_b = (const float*)d_in[8];
    const float* en_W = (const float*)d_in[9];    const float* en_b = (const float*)d_in[10];
    const float* aA_Wq = (const float*)d_in[11];  const float* aA_Wk = (const float*)d_in[12];
    const float* aA_Wv = (const float*)d_in[13];  const float* aA_Wo = (const float*)d_in[14];
    const float* aE_Wq = (const float*)d_in[15];  const float* aE_Wk = (const float*)d_in[16];
    const float* aE_Wv = (const float*)d_in[17];  const float* aE_Wo = (const float*)d_in[18];
    const float* fuse_W1 = (const float*)d_in[19]; const float* fuse_b1 = (const float*)d_in[20];
    const float* fuse_g1 = (const float*)d_in[21]; const float* fuse_be1 = (const float*)d_in[22];
    const float* fuse_W2 = (const float*)d_in[23]; const float* fuse_b2 = (const float*)d_in[24];
    const float* pool_W1 = (const float*)d_in[25]; const float* pool_b1 = (const float*)d_in[26];
    const float* pool_g1 = (const float*)d_in[27]; const float* pool_be1 = (const float*)d_in[28];
    const float* pool_W2 = (const float*)d_in[29]; const float* pool_b2 = (const float*)d_in[30];
    const float* role_W1 = (const float*)d_in[31]; const float* role_b1 = (const float*)d_in[32];
    const float* role_g1 = (const float*)d_in[33]; const float* role_be1 = (const float*)d_in[34];
    const float* role_W2 = (const float*)d_in[35]; const float* role_b2 = (const float*)d_in[36];
    const float* rln_g = (const float*)d_in[37];   const float* rln_b = (const float*)d_in[38];
    const float* gru_Wih = (const float*)d_in[39]; const float* gru_Whh = (const float*)d_in[40];
    const float* gru_bih = (const float*)d_in[41]; const float* gru_bhh = (const float*)d_in[42];
    const float* qn_W = (const float*)d_in[43];    const float* qn_b = (const float*)d_in[44];
    const float* qp_W = (const float*)d_in[45];    const float* kp_W = (const float*)d_in[46];

    char* wsp = (char*)d_ws;
    size_t off = 0;
    auto alloc = [&](size_t bytes) { void* p = wsp + off; off = (off + bytes + 255) & ~(size_t)255; return p; };

    unsigned short* X    = (unsigned short*)alloc((size_t)MROWS * 360 * 2);
    unsigned short* XG   = (unsigned short*)alloc((size_t)MROWS * 520 * 2);
    unsigned short* FPC  = (unsigned short*)alloc((size_t)MROWS * 384 * 2);
    unsigned short* GIb  = (unsigned short*)alloc((size_t)MROWS * 1024 * 2);
    unsigned short* XQ   = (unsigned short*)alloc((size_t)MROWS * 264 * 2);
    unsigned short* T2b  = (unsigned short*)alloc((size_t)MROWS * 128 * 2);
    unsigned short* T3b  = (unsigned short*)alloc((size_t)MROWS * 128 * 2);
    unsigned short* QWSb = (unsigned short*)alloc((size_t)MROWS * 40 * 2);
    // composed bf16 weights
    unsigned short* FPW  = (unsigned short*)alloc(384 * 360 * 2);
    unsigned short* WRZ  = (unsigned short*)alloc(512 * 520 * 2);
    unsigned short* WIN  = (unsigned short*)alloc(256 * 264 * 2);
    unsigned short* WHN  = (unsigned short*)alloc(256 * 256 * 2);
    unsigned short* QWSW = (unsigned short*)alloc(40 * 264 * 2);
    unsigned short* rpW  = (unsigned short*)alloc(128 * 128 * 2);
    // fp32 scratch
    float* WkAp = (float*)alloc(256 * 32 * 4);
    float* WvAp = (float*)alloc(256 * 32 * 4);
    float* WkEp = (float*)alloc(256 * 32 * 4);
    float* WvEp = (float*)alloc(256 * 32 * 4);
    float* Wkpp = (float*)alloc(256 * 32 * 4);
    float* WQKS_AE = (float*)alloc(256 * 256 * 4);
    float* WQKSO = (float*)alloc(256 * 32 * 4);
    float* WoVA = (float*)alloc(256 * 128 * 4);
    float* WoVE = (float*)alloc(256 * 128 * 4);
    float* bvAp = (float*)alloc(256 * 4);
    float* bvEp = (float*)alloc(256 * 4);
    float* bkpp = (float*)alloc(256 * 4);
    float* vall = (float*)alloc(768 * 4);
    float* qksb = (float*)alloc(256 * 4);
    float* fpb  = (float*)alloc(384 * 4);
    float* gibbig = (float*)alloc(768 * 4);
    float* rpb  = (float*)alloc(128 * 4);

    float* Qout = (float*)d_out;
    float* Hout = Qout + (size_t)MROWS * 22;

    auto tilesOf = [](const TOp& o) {
        return o.nb * (((o.I + 31) / 32) * ((o.J + 31) / 32));
    };

    // ---- hidden -> XG cols 264..520 ----
    cvt_hidden<<<MROWS / 4, 256, 0, stream>>>(hidden, XG);

    // ---- mv1: bias projections from raw inputs ----
    {
        MOpSet S; S.n = 5; int waves = 0;
        auto add = [&](MOp o) { S.ops[S.n - 5 + 0] = o; };  // unused
        S.ops[0] = {aA_Wv, 256, ally_b, nullptr, nullptr, bvAp, 256, 256};
        S.ops[1] = {aE_Wv, 256, en_b, nullptr, nullptr, bvEp, 256, 256};
        S.ops[2] = {kp_W, 256, en_b, nullptr, nullptr, bkpp, 256, 256};
        S.ops[3] = {nullptr, 0, nullptr, own_b, nullptr, vall, 256, 0};
        S.ops[4] = {role_W1, 128, pool_b2, role_b1, nullptr, rpb, 128, 128};
        for (int i = 0; i < S.n; i++) { S.waves[i] = S.ops[i].I; waves += S.ops[i].I; }
        mv_ops<<<(waves + 3) / 4, 256, 0, stream>>>(S);
    }
    // ---- T1: W(k/v/kp) composed with entity embeds (fp32) ----
    {
        TOpSet S; S.n = 0; int grid = 0;
        auto add = [&](TOp o) { S.tiles[S.n] = tilesOf(o); grid += S.tiles[S.n]; S.ops[S.n++] = o; };
        add({1, aA_Wk, 256, 1, ally_W, 1, 32, WkAp, 32, 256, 32, 256, 1, 0, 0, 0});
        add({1, aA_Wv, 256, 1, ally_W, 1, 32, WvAp, 32, 256, 32, 256, 1, 0, 0, 0});
        add({1, aE_Wk, 256, 1, en_W, 1, 32, WkEp, 32, 256, 32, 256, 1, 0, 0, 0});
        add({1, aE_Wv, 256, 1, en_W, 1, 32, WvEp, 32, 256, 32, 256, 1, 0, 0, 0});
        add({1, kp_W, 256, 1, en_W, 1, 32, Wkpp, 32, 256, 32, 256, 1, 0, 0, 0});
        compose_tiled<<<grid, 256, 0, stream>>>(S);
    }
    // ---- T2: per-head QK compose + Wo@Wv compose (fp32) ----
    {
        TOpSet S; S.n = 0; int grid = 0;
        auto add = [&](TOp o) { S.tiles[S.n] = tilesOf(o); grid += S.tiles[S.n]; S.ops[S.n++] = o; };
        add({1, WkAp, 1, 32, aA_Wq, 1, 256, WQKS_AE, 256, 32, 256, 64, 4, 2048, 16384, 8192});
        add({1, WkEp, 1, 32, aE_Wq, 1, 256, WQKS_AE + 128 * 256, 256, 32, 256, 64, 4, 2048, 16384, 8192});
        add({1, aA_Wo, 256, 1, WvAp, 1, 32, WoVA, 128, 256, 32, 64, 4, 64, 2048, 32});
        add({1, aE_Wo, 256, 1, WvEp, 1, 32, WoVE, 128, 256, 32, 64, 4, 64, 2048, 32});
        compose_tiled<<<grid, 256, 0, stream>>>(S);
    }
    // ---- mv2: cbA/cbE into vall, qksb ----
    {
        MOpSet S; S.n = 3; int waves = 0;
        S.ops[0] = {aA_Wo, 256, bvAp, nullptr, nullptr, vall + 256, 256, 256};
        S.ops[1] = {aE_Wo, 256, bvEp, nullptr, nullptr, vall + 512, 256, 256};
        S.ops[2] = {WQKS_AE, 256, own_b, nullptr, nullptr, qksb, 256, 256};
        for (int i = 0; i < S.n; i++) { S.waves[i] = S.ops[i].I; waves += S.ops[i].I; }
        mv_ops<<<(waves + 3) / 4, 256, 0, stream>>>(S);
    }
    // ---- mv3: fused biases ----
    {
        MOpSet S; S.n = 4; int waves = 0;
        S.ops[0] = {fuse_W1, 768, vall, fuse_b1, nullptr, fpb, 256, 768};
        S.ops[1] = {pool_W1, 768, vall, pool_b1, nullptr, fpb + 256, 128, 256};
        S.ops[2] = {gru_Wih, 264, fuse_b2, gru_bih, gru_bhh, gibbig, 512, 256};
        S.ops[3] = {gru_Wih + 512 * 264, 264, fuse_b2, gru_bih + 512, nullptr, gibbig + 512, 256, 256};
        for (int i = 0; i < S.n; i++) { S.waves[i] = S.ops[i].I; waves += S.ops[i].I; }
        mv_ops<<<(waves + 3) / 4, 256, 0, stream>>>(S);
    }
    // ---- T3: final composed weights ----
    {
        TOpSet S; S.n = 0; int grid = 0;
        auto add = [&](TOp o) { S.tiles[S.n] = tilesOf(o); grid += S.tiles[S.n]; S.ops[S.n++] = o; };
        // FPW rows 0..256 (fuse)
        add({0, fuse_W1, 768, 1, own_W, 1, 32, FPW, 360, 256, 32, 256, 1, 0, 0, 0});
        add({3, nullptr, 0, 0, nullptr, 0, 0, FPW + 32, 360, 256, 72, 0, 1, 0, 0, 0});
        add({0, fuse_W1 + 256, 768, 1, WoVA, 1, 128, FPW + 104, 360, 256, 128, 256, 1, 0, 0, 0});
        add({0, fuse_W1 + 512, 768, 1, WoVE, 1, 128, FPW + 232, 360, 256, 128, 256, 1, 0, 0, 0});
        // FPW rows 256..384 (pool)
        add({0, pool_W1, 768, 1, own_W, 1, 32, FPW + 256 * 360, 360, 128, 32, 256, 1, 0, 0, 0});
        add({0, pool_W1 + 256, 768, 1, ally_W, 1, 32, FPW + 256 * 360 + 32, 360, 128, 32, 256, 1, 0, 0, 0});
        add({0, pool_W1 + 512, 768, 1, en_W, 1, 32, FPW + 256 * 360 + 64, 360, 128, 32, 256, 1, 0, 0, 0});
        add({0, pool_W1 + 256, 768, 1, ally_b, 0, 1, FPW + 256 * 360 + 96, 360, 128, 1, 256, 1, 0, 0, 0});
        add({0, pool_W1 + 512, 768, 1, en_b, 0, 1, FPW + 256 * 360 + 97, 360, 128, 1, 256, 1, 0, 0, 0});
        add({3, nullptr, 0, 0, nullptr, 0, 0, FPW + 256 * 360 + 98, 360, 128, 6, 0, 1, 0, 0, 0});
        add({3, nullptr, 0, 0, nullptr, 0, 0, FPW + 256 * 360 + 104, 360, 128, 256, 0, 1, 0, 0, 0});
        // GRU weights
        add({0, gru_Wih, 264, 1, fuse_W2, 1, 256, WRZ, 520, 512, 256, 256, 1, 0, 0, 0});
        add({2, gru_Wih + 256, 264, 1, nullptr, 0, 0, WRZ + 256, 520, 512, 8, 0, 1, 0, 0, 0});
        add({2, gru_Whh, 256, 1, nullptr, 0, 0, WRZ + 264, 520, 512, 256, 0, 1, 0, 0, 0});
        add({0, gru_Wih + 512 * 264, 264, 1, fuse_W2, 1, 256, WIN, 264, 256, 256, 256, 1, 0, 0, 0});
        add({2, gru_Wih + 512 * 264 + 256, 264, 1, nullptr, 0, 0, WIN + 256, 264, 256, 8, 0, 1, 0, 0, 0});
        add({2, gru_Whh + 512 * 256, 256, 1, nullptr, 0, 0, WHN, 256, 256, 256, 0, 1, 0, 0, 0});
        // QWSW
        add({0, Wkpp, 1, 32, qp_W, 1, 264, QWSW, 264, 32, 264, 256, 1, 0, 0, 0});
        add({0, bkpp, 0, 1, qp_W, 1, 264, QWSW + 32 * 264, 264, 1, 264, 256, 1, 0, 0, 0});
        add({2, qn_W, 256, 1, nullptr, 0, 0, QWSW + 33 * 264, 264, 6, 256, 0, 1, 0, 0, 0});
        add({3, nullptr, 0, 0, nullptr, 0, 0, QWSW + 33 * 264 + 256, 264, 6, 8, 0, 1, 0, 0, 0});
        add({3, nullptr, 0, 0, nullptr, 0, 0, QWSW + 39 * 264, 264, 1, 264, 0, 1, 0, 0, 0});
        // WQKSO (fp32, for glue_attn)
        add({1, WQKS_AE, 256, 1, own_W, 1, 32, WQKSO, 32, 256, 32, 256, 1, 0, 0, 0});
        // rpW = role_W1 @ pool_W2
        add({0, role_W1, 128, 1, pool_W2, 1, 128, rpW, 128, 128, 128, 128, 1, 0, 0, 0});
        compose_tiled<<<grid, 256, 0, stream>>>(S);
    }

    auto gemm = [&](const unsigned short* A, int lda, const unsigned short* Wm, const float* bias,
                    unsigned short* C, int ldc, int N, int K, int act) {
        gemm_bf16<<<dim3(MROWS / 128, (N + 127) / 128), 256, 0, stream>>>(A, lda, Wm, bias, C, ldc, N, K, act);
    };

    // ---- main chain ----
    glue_attn<<<MROWS / 4, 256, 0, stream>>>(ally_feats, enemy_feats, own_feats, WQKSO, qksb, X);
    gemm(X, 360, FPW, fpb, FPC, 384, 384, 360, 1);                    // fuse1+pool1 (+gelu)
    ln_fp<<<MROWS, 384, 0, stream>>>(FPC, fuse_g1, fuse_be1, pool_g1, pool_be1, XG, T2b);
    gemm(T2b, 128, rpW, rpb, T3b, 128, 128, 128, 1);                  // role1 (pool_W2 folded) + gelu
    ln_bf16<<<MROWS, 128, 0, stream>>>(T3b, 128, role_g1, role_be1, 128);
    glue_role<<<MROWS / 32, 256, 0, stream>>>(T3b, role_W2, role_b2, rln_g, rln_b, XG);
    gemm(XG, 520, WRZ, gibbig, GIb, 1024, 512, 520, 0);               // r,z (i+h summed)
    gemm(XG, 520, WIN, gibbig + 512, GIb + 512, 1024, 256, 264, 0);   // i_n
    gemm(XG + 264, 520, WHN, gru_bhh + 512, GIb + 768, 1024, 256, 256, 0); // h_n
    glue_gru<<<MROWS, 256, 0, stream>>>(GIb, hidden, Hout, XQ, XG);
    gemm(XQ, 264, QWSW, nullptr, QWSb, 40, 40, 264, 0);               // qws + c0 + q_normal
    glue_final<<<MROWS / 8, 256, 0, stream>>>(QWSb, enemy_feats, qn_b, Qout);
}

// Round 4
// 485.950 us; speedup vs baseline: 2.4026x; 1.2166x over previous
//
#include <hip/hip_runtime.h>
#include <hip/hip_bf16.h>

// CAPERNN_ContRoles_HPN — round 4: m97-style GEMM (global_load_lds width-16, pad-free LDS),
// QKS back to MFMA GEMM, merged GRU GEMM (N=1024,K=520), fused ln+role kernel.
// M = BN = 16384, H=256, NH=4, HD=64, NA=15, NE=16, RD=8, NMOVE=6.

#define MROWS 16384

typedef __attribute__((ext_vector_type(8))) short short8;
typedef __attribute__((ext_vector_type(4))) float float4v;

__device__ __forceinline__ unsigned short f2b(float f) {
    __hip_bfloat16 h = __float2bfloat16(f);
    return *reinterpret_cast<unsigned short*>(&h);
}
__device__ __forceinline__ float b2f(unsigned short u) {
    __hip_bfloat16 h;
    *reinterpret_cast<unsigned short*>(&h) = u;
    return __bfloat162float(h);
}
__device__ __forceinline__ void gll16(const unsigned short* g, unsigned short* l) {
    __builtin_amdgcn_global_load_lds((const __attribute__((address_space(1))) void*)g,
                                     (__attribute__((address_space(3))) void*)l, 16, 0, 0);
}

// ---------------- prep: hidden->XG[264:520], own->OWNb, zero zbuf ----------------
__global__ void cvt_misc(const float* __restrict__ hidden, const float* __restrict__ ownf,
                         unsigned short* __restrict__ XG, unsigned short* __restrict__ OWNb,
                         unsigned short* __restrict__ zbuf) {
    int idx = blockIdx.x * 256 + threadIdx.x;
    const int nh = MROWS * 64;        // hidden: 4 elems/thread
    const int no = MROWS * 8;         // own: 4 elems/thread
    if (idx < nh) {
        int row = idx >> 6, c4 = (idx & 63) * 4;
        float4 v = *(const float4*)(hidden + (size_t)row * 256 + c4);
        unsigned short* d = XG + (size_t)row * 520 + 264 + c4;
        d[0] = f2b(v.x); d[1] = f2b(v.y); d[2] = f2b(v.z); d[3] = f2b(v.w);
    } else if (idx < nh + no) {
        int j = idx - nh;
        int row = j >> 3, c4 = (j & 7) * 4;
        float4 v = *(const float4*)(ownf + (size_t)row * 32 + c4);
        unsigned short* d = OWNb + (size_t)row * 32 + c4;
        d[0] = f2b(v.x); d[1] = f2b(v.y); d[2] = f2b(v.z); d[3] = f2b(v.w);
    } else if (idx < nh + no + 16) {
        int j = idx - nh - no;
        ((uint4*)zbuf)[j] = make_uint4(0u, 0u, 0u, 0u);   // 256 B zeros
    }
}

// ---------------- tiled compose: 32x32 output tiles, LDS-staged ----------------
// type 0: matmul->bf16, 1: matmul->fp32, 2: cvt copy->bf16, 3: zero bf16
struct TOp {
    int type;
    const float* A; int sAi, sAk;
    const float* B; int sBj, sBk;
    void* O; int sOi;
    int I, J, K;
    int nb; int aB, bB, oB;
};
struct TOpSet { int n; int tiles[26]; TOp ops[26]; };

__global__ __launch_bounds__(256)
void compose_tiled(TOpSet S) {
    int t = blockIdx.x;
    int op = 0;
    while (op < S.n && t >= S.tiles[op]) { t -= S.tiles[op]; op++; }
    if (op >= S.n) return;
    TOp o = S.ops[op];
    int ti = (o.I + 31) >> 5, tj = (o.J + 31) >> 5;
    int per = ti * tj;
    int b = t / per;
    int rem = t - b * per;
    int i0 = (rem / tj) * 32, j0 = (rem % tj) * 32;
    int tid = threadIdx.x;
    if (o.type >= 2) {
        for (int e = tid; e < 1024; e += 256) {
            int r = e >> 5, c = e & 31;
            int i = i0 + r, j = j0 + c;
            if (i < o.I && j < o.J) {
                unsigned short v = 0;
                if (o.type == 2) v = f2b(o.A[(long)b * o.aB + (long)i * o.sAi + (long)j * o.sAk]);
                ((unsigned short*)o.O)[(long)b * o.oB + (long)i * o.sOi + j] = v;
            }
        }
        return;
    }
    __shared__ float As[32][33];
    __shared__ float Bs[32][33];
    int tx = tid & 15, ty = tid >> 4;
    float a00 = 0.f, a01 = 0.f, a10 = 0.f, a11 = 0.f;
    const float* Ab = o.A + (long)b * o.aB;
    const float* Bb = o.B + (long)b * o.bB;
    for (int k0 = 0; k0 < o.K; k0 += 32) {
        for (int e = tid; e < 1024; e += 256) {
            int r = e >> 5, c = e & 31;
            As[r][c] = (i0 + r < o.I && k0 + c < o.K)
                       ? Ab[(long)(i0 + r) * o.sAi + (long)(k0 + c) * o.sAk] : 0.f;
            Bs[r][c] = (k0 + r < o.K && j0 + c < o.J)
                       ? Bb[(long)(j0 + c) * o.sBj + (long)(k0 + r) * o.sBk] : 0.f;
        }
        __syncthreads();
#pragma unroll
        for (int k = 0; k < 32; k++) {
            float x0 = As[ty * 2][k], x1 = As[ty * 2 + 1][k];
            float y0 = Bs[k][tx * 2], y1 = Bs[k][tx * 2 + 1];
            a00 += x0 * y0; a01 += x0 * y1; a10 += x1 * y0; a11 += x1 * y1;
        }
        __syncthreads();
    }
    int i = i0 + ty * 2, j = j0 + tx * 2;
    float vals[2][2] = {{a00, a01}, {a10, a11}};
#pragma unroll
    for (int di = 0; di < 2; di++)
#pragma unroll
        for (int dj = 0; dj < 2; dj++) {
            int ii = i + di, jj = j + dj;
            if (ii < o.I && jj < o.J) {
                long oidx = (long)b * o.oB + (long)ii * o.sOi + jj;
                if (o.type == 0) ((unsigned short*)o.O)[oidx] = f2b(vals[di][dj]);
                else ((float*)o.O)[oidx] = vals[di][dj];
            }
        }
}

// ---------------- matvec ops: one wave per output ----------------
struct MOp { const float* A; int sAi; const float* x; const float* b1; const float* b2; float* out; int I, K; };
struct MOpSet { int n; int waves[10]; MOp ops[10]; };

__global__ void mv_ops(MOpSet S) {
    int wid = blockIdx.x * 4 + (threadIdx.x >> 6);
    int lane = threadIdx.x & 63;
    int op = 0;
    while (op < S.n && wid >= S.waves[op]) { wid -= S.waves[op]; op++; }
    if (op >= S.n) return;
    MOp o = S.ops[op];
    float s = 0.f;
    for (int k = lane; k < o.K; k += 64) s += o.A[(long)wid * o.sAi + k] * o.x[k];
    for (int off = 32; off; off >>= 1) s += __shfl_xor(s, off, 64);
    if (lane == 0) {
        if (o.b1) s += o.b1[wid];
        if (o.b2) s += o.b2[wid];
        o.out[wid] = s;
    }
}

// ---------------- bf16 MFMA GEMM: C[MxN] = A[MxK] @ W[NxK]^T (+bias)(+gelu) ----------------
// m97 structure: global_load_lds width-16, pad-free [128][32] LDS, 4 waves 2x2, 4x4 mfma tiles.
__global__ __launch_bounds__(256, 4)
void gemm_bf16(const unsigned short* __restrict__ A, int lda,
               const unsigned short* __restrict__ W,
               const float* __restrict__ bias,
               unsigned short* __restrict__ C, int ldc,
               int N, int K, int act,
               const unsigned short* __restrict__ zbuf) {
    __shared__ __align__(16) unsigned short As[128 * 32];
    __shared__ __align__(16) unsigned short Bs[128 * 32];
    int tid = threadIdx.x;
    int m0 = blockIdx.x * 128, n0 = blockIdx.y * 128;
    int wave = tid >> 6, lane = tid & 63;
    int wm = (wave & 1) * 64, wn = (wave >> 1) * 64;
    int l16 = lane & 15, quad = lane >> 4;

    float4v acc[4][4];
#pragma unroll
    for (int i = 0; i < 4; i++)
#pragma unroll
        for (int j = 0; j < 4; j++) acc[i][j] = (float4v){0.f, 0.f, 0.f, 0.f};

    int s0 = tid, s1 = tid + 256;
    int row0 = s0 >> 2, seg0 = (s0 & 3) * 8;
    int row1 = s1 >> 2, seg1 = (s1 & 3) * 8;
    const unsigned short* Arow0 = A + (size_t)(m0 + row0) * lda;
    const unsigned short* Arow1 = A + (size_t)(m0 + row1) * lda;
    const unsigned short* Wrow0 = (n0 + row0 < N) ? W + (size_t)(n0 + row0) * K : nullptr;
    const unsigned short* Wrow1 = (n0 + row1 < N) ? W + (size_t)(n0 + row1) * K : nullptr;
    unsigned short* ldsA0 = As + (size_t)(wave * 64) * 8;
    unsigned short* ldsA1 = As + (size_t)(wave * 64 + 256) * 8;
    unsigned short* ldsB0 = Bs + (size_t)(wave * 64) * 8;
    unsigned short* ldsB1 = Bs + (size_t)(wave * 64 + 256) * 8;

    for (int k0 = 0; k0 < K; k0 += 32) {
        int ka0 = k0 + seg0, ka1 = k0 + seg1;
        gll16((ka0 < K) ? Arow0 + ka0 : zbuf, ldsA0);
        gll16((ka1 < K) ? Arow1 + ka1 : zbuf, ldsA1);
        gll16((ka0 < K && Wrow0) ? Wrow0 + ka0 : zbuf, ldsB0);
        gll16((ka1 < K && Wrow1) ? Wrow1 + ka1 : zbuf, ldsB1);
        __syncthreads();
        short8 a[4], b[4];
#pragma unroll
        for (int i = 0; i < 4; i++) {
            a[i] = *(const short8*)(&As[(wm + i * 16 + l16) * 32 + quad * 8]);
            b[i] = *(const short8*)(&Bs[(wn + i * 16 + l16) * 32 + quad * 8]);
        }
#pragma unroll
        for (int i = 0; i < 4; i++)
#pragma unroll
            for (int j = 0; j < 4; j++)
                acc[i][j] = __builtin_amdgcn_mfma_f32_16x16x32_bf16(a[i], b[j], acc[i][j], 0, 0, 0);
        __syncthreads();
    }
#pragma unroll
    for (int i = 0; i < 4; i++) {
#pragma unroll
        for (int j = 0; j < 4; j++) {
#pragma unroll
            for (int rr = 0; rr < 4; rr++) {
                int rowm = m0 + wm + i * 16 + quad * 4 + rr;
                int coln = wn + j * 16 + l16;
                if (n0 + coln >= N) continue;
                float v = acc[i][j][rr];
                if (bias) v += bias[n0 + coln];
                if (act == 1) v = 0.5f * v * (1.f + erff(v * 0.70710678f));
                C[(size_t)rowm * ldc + n0 + coln] = f2b(v);
            }
        }
    }
}

// ---------------- combined LN: FPC[:,0:256]->XG(ld520), FPC[:,256:384]->T2 ----------------
__global__ void ln_fp(const unsigned short* __restrict__ FPC,
                      const float* __restrict__ g1, const float* __restrict__ be1,
                      const float* __restrict__ g2, const float* __restrict__ be2,
                      unsigned short* __restrict__ XG, unsigned short* __restrict__ T2) {
    int row = blockIdx.x, t = threadIdx.x;
    float v = b2f(FPC[(size_t)row * 384 + t]);
    float s = v, q = v * v;
    for (int o = 32; o; o >>= 1) { s += __shfl_xor(s, o, 64); q += __shfl_xor(q, o, 64); }
    __shared__ float rs[6], rq[6];
    int w = t >> 6;
    if ((t & 63) == 0) { rs[w] = s; rq[w] = q; }
    __syncthreads();
    if (t < 256) {
        float ts = rs[0] + rs[1] + rs[2] + rs[3], tq = rq[0] + rq[1] + rq[2] + rq[3];
        float mean = ts * (1.f / 256.f);
        float var = tq * (1.f / 256.f) - mean * mean;
        float o = (v - mean) * rsqrtf(var + 1e-5f) * g1[t] + be1[t];
        XG[(size_t)row * 520 + t] = f2b(o);
    } else {
        int tt = t - 256;
        float ts = rs[4] + rs[5], tq = rq[4] + rq[5];
        float mean = ts * (1.f / 128.f);
        float var = tq * (1.f / 128.f) - mean * mean;
        float o = (v - mean) * rsqrtf(var + 1e-5f) * g2[tt] + be2[tt];
        T2[(size_t)row * 128 + tt] = f2b(o);
    }
}

// ---------------- attention glue: softmax + weighted feats + means (4 rows/block) ----------------
__global__ __launch_bounds__(256)
void glue_attn(const float* __restrict__ allyf, const float* __restrict__ enemyf,
               const float* __restrict__ ownf, const unsigned short* __restrict__ QKS,
               unsigned short* __restrict__ X) {
    __shared__ float af[4][495];    // 15 x 33
    __shared__ float ef[4][528];    // 16 x 33
    __shared__ float qk[4][256];
    __shared__ float attnA[4][64];
    __shared__ float attnE[4][64];
    __shared__ float mskA[4][16];
    __shared__ float mskE[4][16];
    int tid = threadIdx.x;
    size_t rb = (size_t)blockIdx.x * 4;

    for (int idx = tid; idx < 1920; idx += 256) {
        int r = idx / 480, w0 = idx % 480;
        af[r][(w0 >> 5) * 33 + (w0 & 31)] = allyf[(rb + r) * 480 + w0];
    }
    for (int idx = tid; idx < 2048; idx += 256) {
        int r = idx >> 9, w0 = idx & 511;
        ef[r][(w0 >> 5) * 33 + (w0 & 31)] = enemyf[(rb + r) * 512 + w0];
    }
    for (int idx = tid; idx < 1024; idx += 256)
        qk[idx >> 8][idx & 255] = b2f(QKS[(rb + (idx >> 8)) * 256 + (idx & 255)]);
    if (tid < 128) {
        int r = tid >> 5, c = tid & 31;
        X[(rb + r) * 360 + c] = f2b(ownf[(rb + r) * 32 + c]);
    } else if (tid < 152) {
        int r = (tid - 128) / 6, c = 98 + (tid - 128) % 6;
        X[(rb + r) * 360 + c] = 0;
    }
    __syncthreads();

    // masks
    {
        int r = tid >> 6, lane = tid & 63;
        if (lane < 15) {
            bool nz = false;
            for (int d = 0; d < 32; d++) nz |= (af[r][lane * 33 + d] != 0.f);
            mskA[r][lane] = nz ? 1.f : 0.f;
        } else if (lane == 15) {
            mskA[r][15] = 0.f;
        } else if (lane < 32) {
            int mm = lane - 16;
            bool nz = false;
            for (int d = 0; d < 32; d++) nz |= (ef[r][mm * 33 + d] != 0.f);
            mskE[r][mm] = nz ? 1.f : 0.f;
        }
    }
    __syncthreads();

    int r = tid >> 6, lane = tid & 63;
    int h = lane >> 4, m = lane & 15;
    // ally softmax (15 entities)
    {
        float sc = -3.0e38f;
        if (m < 15) {
            float s = 0.f;
            for (int d = 0; d < 32; d++) s += qk[r][h * 32 + d] * af[r][m * 33 + d];
            sc = (mskA[r][m] > 0.f) ? s * 0.125f : -1e9f;
        }
        float mx = sc;
        for (int o = 8; o; o >>= 1) mx = fmaxf(mx, __shfl_xor(mx, o, 64));
        float e = (m < 15) ? __expf(sc - mx) : 0.f;
        float sm = e;
        for (int o = 8; o; o >>= 1) sm += __shfl_xor(sm, o, 64);
        attnA[r][h * 16 + m] = e / sm;
    }
    // enemy softmax (16 entities)
    {
        float s = 0.f;
        for (int d = 0; d < 32; d++) s += qk[r][128 + h * 32 + d] * ef[r][m * 33 + d];
        float sc = (mskE[r][m] > 0.f) ? s * 0.125f : -1e9f;
        float mx = sc;
        for (int o = 8; o; o >>= 1) mx = fmaxf(mx, __shfl_xor(mx, o, 64));
        float e = __expf(sc - mx);
        float sm = e;
        for (int o = 8; o; o >>= 1) sm += __shfl_xor(sm, o, 64);
        attnE[r][h * 16 + m] = e / sm;
    }
    __syncthreads();
    size_t row = rb + r;
#pragma unroll
    for (int it = 0; it < 2; it++) {
        int idx = lane + it * 64;
        int hh = idx >> 5, c = idx & 31;
        float sA = 0.f;
        for (int mm = 0; mm < 15; mm++) sA += attnA[r][hh * 16 + mm] * af[r][mm * 33 + c];
        X[row * 360 + 104 + idx] = f2b(sA);
        float sE = 0.f;
        for (int mm = 0; mm < 16; mm++) sE += attnE[r][hh * 16 + mm] * ef[r][mm * 33 + c];
        X[row * 360 + 232 + idx] = f2b(sE);
    }
    if (lane < 32) {
        float cnt = 0.f;
        for (int mm = 0; mm < 15; mm++) cnt += mskA[r][mm];
        float s = 0.f;
        for (int mm = 0; mm < 15; mm++) s += af[r][mm * 33 + lane];
        X[row * 360 + 32 + lane] = f2b(s / fmaxf(cnt, 1e-8f));
        if (lane == 0) X[row * 360 + 96] = f2b(cnt > 0.f ? 1.f : 0.f);
    } else {
        int c = lane - 32;
        float cnt = 0.f;
        for (int mm = 0; mm < 16; mm++) cnt += mskE[r][mm];
        float s = 0.f;
        for (int mm = 0; mm < 16; mm++) s += ef[r][mm * 33 + c];
        X[row * 360 + 64 + c] = f2b(s / fmaxf(cnt, 1e-8f));
        if (c == 0) X[row * 360 + 97] = f2b(cnt > 0.f ? 1.f : 0.f);
    }
}

// ---------------- fused LN(128) + role head -> XG cols 256..264 ----------------
__global__ __launch_bounds__(256)
void ln_role(const unsigned short* __restrict__ T3, const float* __restrict__ g1,
             const float* __restrict__ be1, const float* __restrict__ W2,
             const float* __restrict__ b2, const float* __restrict__ rg,
             const float* __restrict__ rb, unsigned short* __restrict__ XG) {
    __shared__ float t3[32][132];
    __shared__ float gl[128], bl[128];
    int tid = threadIdx.x;
    size_t base = (size_t)blockIdx.x * 4096;
    for (int idx = tid; idx < 4096; idx += 256)
        t3[idx >> 7][idx & 127] = b2f(T3[base + idx]);
    if (tid < 128) { gl[tid] = g1[tid]; bl[tid] = be1[tid]; }
    __syncthreads();
    int r = tid >> 3, t = tid & 7;
    float s = 0.f, q = 0.f;
    for (int c = 0; c < 16; c++) { float v = t3[r][t * 16 + c]; s += v; q += v * v; }
    for (int o = 4; o; o >>= 1) { s += __shfl_xor(s, o, 8); q += __shfl_xor(q, o, 8); }
    float mean = s * (1.f / 128.f);
    float var = q * (1.f / 128.f) - mean * mean;
    float rstd = rsqrtf(var + 1e-5f);
    float acc = b2[t];
    const float* w = W2 + t * 128;
    for (int d = 0; d < 128; d++)
        acc += w[d] * ((t3[r][d] - mean) * rstd * gl[d] + bl[d]);
    float v = tanhf(acc);
    float mn = v;
    for (int o = 4; o; o >>= 1) mn += __shfl_xor(mn, o, 8);
    mn *= 0.125f;
    float dv = v - mn, qq = dv * dv;
    for (int o = 4; o; o >>= 1) qq += __shfl_xor(qq, o, 8);
    qq *= 0.125f;
    size_t row = (size_t)blockIdx.x * 32 + r;
    XG[row * 520 + 256 + t] = f2b(dv * rsqrtf(qq + 1e-5f) * rg[t] + rb[t]);
}

// ---------------- GRU glue (G cols: 0..256 r-sum, 256..512 z-sum, 512..768 i_n, 768..1024 h_n) ----
__global__ void glue_gru(const unsigned short* __restrict__ G, const float* __restrict__ hp,
                         float* __restrict__ hout, unsigned short* __restrict__ XQ,
                         const unsigned short* __restrict__ XG) {
    size_t row = blockIdx.x;
    int i = threadIdx.x;
    size_t b = row * 1024;
    float rg = 1.f / (1.f + __expf(-b2f(G[b + i])));
    float zg = 1.f / (1.f + __expf(-b2f(G[b + 256 + i])));
    float ng = tanhf(b2f(G[b + 512 + i]) + rg * b2f(G[b + 768 + i]));
    float h = (1.f - zg) * ng + zg * hp[row * 256 + i];
    hout[row * 256 + i] = h;
    XQ[row * 264 + i] = f2b(h);
    if (i < 8) XQ[row * 264 + 256 + i] = XG[row * 520 + 256 + i];
}

// ---------------- final heads ----------------
__global__ __launch_bounds__(256)
void glue_final(const unsigned short* __restrict__ QWS, const float* __restrict__ efeats,
                const float* __restrict__ qnb, float* __restrict__ Q) {
    __shared__ float ef[8][528];
    __shared__ float qw[8][40];
    int tid = threadIdx.x;
    size_t rb = (size_t)blockIdx.x * 8;
    for (int idx = tid; idx < 4096; idx += 256) {
        int r = idx >> 9, w0 = idx & 511;
        ef[r][(w0 >> 5) * 33 + (w0 & 31)] = efeats[(rb + r) * 512 + w0];
    }
    for (int idx = tid; idx < 320; idx += 256) {
        int r = idx / 40, c = idx % 40;
        qw[r][c] = b2f(QWS[(rb + r) * 40 + c]);
    }
    __syncthreads();
    int r = tid >> 5, t = tid & 31;
    size_t row = rb + r;
    float lg = 0.f, mk = 0.f;
    if (t < 16) {
        const float* fr = ef[r] + t * 33;
        bool nz = false;
        float s = 0.f;
        for (int d = 0; d < 32; d++) { nz |= (fr[d] != 0.f); s += qw[r][d] * fr[d]; }
        mk = nz ? 1.f : 0.f;
        lg = (s + qw[r][32]) * 0.0625f;
    }
    float sv = mk * lg, cv = mk;
    for (int o = 8; o; o >>= 1) { sv += __shfl_xor(sv, o, 64); cv += __shfl_xor(cv, o, 64); }
    float mean = sv / fmaxf(cv, 1.f);
    if (t < 16) Q[row * 22 + 6 + t] = (mk > 0.f ? lg : -1e9f) - mean;
    if (t < 6) Q[row * 22 + t] = qw[r][33 + t] + qnb[t];
}

// ---------------- host orchestration ----------------
extern "C" void kernel_launch(void* const* d_in, const int* in_sizes, int n_in,
                              void* d_out, int out_size, void* d_ws, size_t ws_size,
                              hipStream_t stream) {
    const float* own_feats = (const float*)d_in[1];
    const float* ally_feats = (const float*)d_in[2];
    const float* enemy_feats = (const float*)d_in[3];
    const float* hidden = (const float*)d_in[4];
    const float* own_W = (const float*)d_in[5];   const float* own_b = (const float*)d_in[6];
    const float* ally_W = (const float*)d_in[7];  const float* ally_b = (const float*)d_in[8];
    const float* en_W = (const float*)d_in[9];    const float* en_b = (const float*)d_in[10];
    const float* aA_Wq = (const float*)d_in[11];  const float* aA_Wk = (const float*)d_in[12];
    const float* aA_Wv = (const float*)d_in[13];  const float* aA_Wo = (const float*)d_in[14];
    const float* aE_Wq = (const float*)d_in[15];  const float* aE_Wk = (const float*)d_in[16];
    const float* aE_Wv = (const float*)d_in[17];  const float* aE_Wo = (const float*)d_in[18];
    const float* fuse_W1 = (const float*)d_in[19]; const float* fuse_b1 = (const float*)d_in[20];
    const float* fuse_g1 = (const float*)d_in[21]; const float* fuse_be1 = (const float*)d_in[22];
    const float* fuse_W2 = (const float*)d_in[23]; const float* fuse_b2 = (const float*)d_in[24];
    const float* pool_W1 = (const float*)d_in[25]; const float* pool_b1 = (const float*)d_in[26];
    const float* pool_g1 = (const float*)d_in[27]; const float* pool_be1 = (const float*)d_in[28];
    const float* pool_W2 = (const float*)d_in[29]; const float* pool_b2 = (const float*)d_in[30];
    const float* role_W1 = (const float*)d_in[31]; const float* role_b1 = (const float*)d_in[32];
    const float* role_g1 = (const float*)d_in[33]; const float* role_be1 = (const float*)d_in[34];
    const float* role_W2 = (const float*)d_in[35]; const float* role_b2 = (const float*)d_in[36];
    const float* rln_g = (const float*)d_in[37];   const float* rln_b = (const float*)d_in[38];
    const float* gru_Wih = (const float*)d_in[39]; const float* gru_Whh = (const float*)d_in[40];
    const float* gru_bih = (const float*)d_in[41]; const float* gru_bhh = (const float*)d_in[42];
    const float* qn_W = (const float*)d_in[43];    const float* qn_b = (const float*)d_in[44];
    const float* qp_W = (const float*)d_in[45];    const float* kp_W = (const float*)d_in[46];

    char* wsp = (char*)d_ws;
    size_t off = 0;
    auto alloc = [&](size_t bytes) { void* p = wsp + off; off = (off + bytes + 255) & ~(size_t)255; return p; };

    unsigned short* X    = (unsigned short*)alloc((size_t)MROWS * 360 * 2);
    unsigned short* XG   = (unsigned short*)alloc((size_t)MROWS * 520 * 2);
    unsigned short* FPC  = (unsigned short*)alloc((size_t)MROWS * 384 * 2);
    unsigned short* GIb  = (unsigned short*)alloc((size_t)MROWS * 1024 * 2);
    unsigned short* XQ   = (unsigned short*)alloc((size_t)MROWS * 264 * 2);
    unsigned short* T2b  = (unsigned short*)alloc((size_t)MROWS * 128 * 2);
    unsigned short* T3b  = (unsigned short*)alloc((size_t)MROWS * 128 * 2);
    unsigned short* QKSb = (unsigned short*)alloc((size_t)MROWS * 256 * 2);
    unsigned short* QWSb = (unsigned short*)alloc((size_t)MROWS * 40 * 2);
    unsigned short* OWNb = (unsigned short*)alloc((size_t)MROWS * 32 * 2);
    // composed bf16 weights
    unsigned short* FPW  = (unsigned short*)alloc(384 * 360 * 2);
    unsigned short* WGRU = (unsigned short*)alloc(1024 * 520 * 2);
    unsigned short* QWSW = (unsigned short*)alloc(40 * 264 * 2);
    unsigned short* WQKSO= (unsigned short*)alloc(256 * 32 * 2);
    unsigned short* rpW  = (unsigned short*)alloc(128 * 128 * 2);
    unsigned short* zbuf = (unsigned short*)alloc(256);
    // fp32 scratch
    float* WkAp = (float*)alloc(256 * 32 * 4);
    float* WvAp = (float*)alloc(256 * 32 * 4);
    float* WkEp = (float*)alloc(256 * 32 * 4);
    float* WvEp = (float*)alloc(256 * 32 * 4);
    float* Wkpp = (float*)alloc(256 * 32 * 4);
    float* WQKS_AE = (float*)alloc(256 * 256 * 4);
    float* WoVA = (float*)alloc(256 * 128 * 4);
    float* WoVE = (float*)alloc(256 * 128 * 4);
    float* bvAp = (float*)alloc(256 * 4);
    float* bvEp = (float*)alloc(256 * 4);
    float* bkpp = (float*)alloc(256 * 4);
    float* vall = (float*)alloc(768 * 4);
    float* qksb = (float*)alloc(256 * 4);
    float* fpb  = (float*)alloc(384 * 4);
    float* gbias= (float*)alloc(1024 * 4);
    float* rpb  = (float*)alloc(128 * 4);

    float* Qout = (float*)d_out;
    float* Hout = Qout + (size_t)MROWS * 22;

    auto tilesOf = [](const TOp& o) {
        return o.nb * (((o.I + 31) / 32) * ((o.J + 31) / 32));
    };

    // ---- prep ----
    cvt_misc<<<(MROWS * 64 + MROWS * 8 + 16 + 255) / 256, 256, 0, stream>>>(hidden, own_feats, XG, OWNb, zbuf);

    {   // mv1
        MOpSet S; S.n = 5; int waves = 0;
        S.ops[0] = {aA_Wv, 256, ally_b, nullptr, nullptr, bvAp, 256, 256};
        S.ops[1] = {aE_Wv, 256, en_b, nullptr, nullptr, bvEp, 256, 256};
        S.ops[2] = {kp_W, 256, en_b, nullptr, nullptr, bkpp, 256, 256};
        S.ops[3] = {nullptr, 0, nullptr, own_b, nullptr, vall, 256, 0};
        S.ops[4] = {role_W1, 128, pool_b2, role_b1, nullptr, rpb, 128, 128};
        for (int i = 0; i < S.n; i++) { S.waves[i] = S.ops[i].I; waves += S.ops[i].I; }
        mv_ops<<<(waves + 3) / 4, 256, 0, stream>>>(S);
    }
    {   // T1
        TOpSet S; S.n = 0; int grid = 0;
        auto add = [&](TOp o) { S.tiles[S.n] = tilesOf(o); grid += S.tiles[S.n]; S.ops[S.n++] = o; };
        add({1, aA_Wk, 256, 1, ally_W, 1, 32, WkAp, 32, 256, 32, 256, 1, 0, 0, 0});
        add({1, aA_Wv, 256, 1, ally_W, 1, 32, WvAp, 32, 256, 32, 256, 1, 0, 0, 0});
        add({1, aE_Wk, 256, 1, en_W, 1, 32, WkEp, 32, 256, 32, 256, 1, 0, 0, 0});
        add({1, aE_Wv, 256, 1, en_W, 1, 32, WvEp, 32, 256, 32, 256, 1, 0, 0, 0});
        add({1, kp_W, 256, 1, en_W, 1, 32, Wkpp, 32, 256, 32, 256, 1, 0, 0, 0});
        compose_tiled<<<grid, 256, 0, stream>>>(S);
    }
    {   // T2
        TOpSet S; S.n = 0; int grid = 0;
        auto add = [&](TOp o) { S.tiles[S.n] = tilesOf(o); grid += S.tiles[S.n]; S.ops[S.n++] = o; };
        add({1, WkAp, 1, 32, aA_Wq, 1, 256, WQKS_AE, 256, 32, 256, 64, 4, 2048, 16384, 8192});
        add({1, WkEp, 1, 32, aE_Wq, 1, 256, WQKS_AE + 128 * 256, 256, 32, 256, 64, 4, 2048, 16384, 8192});
        add({1, aA_Wo, 256, 1, WvAp, 1, 32, WoVA, 128, 256, 32, 64, 4, 64, 2048, 32});
        add({1, aE_Wo, 256, 1, WvEp, 1, 32, WoVE, 128, 256, 32, 64, 4, 64, 2048, 32});
        compose_tiled<<<grid, 256, 0, stream>>>(S);
    }
    {   // mv2
        MOpSet S; S.n = 3; int waves = 0;
        S.ops[0] = {aA_Wo, 256, bvAp, nullptr, nullptr, vall + 256, 256, 256};
        S.ops[1] = {aE_Wo, 256, bvEp, nullptr, nullptr, vall + 512, 256, 256};
        S.ops[2] = {WQKS_AE, 256, own_b, nullptr, nullptr, qksb, 256, 256};
        for (int i = 0; i < S.n; i++) { S.waves[i] = S.ops[i].I; waves += S.ops[i].I; }
        mv_ops<<<(waves + 3) / 4, 256, 0, stream>>>(S);
    }
    {   // mv3
        MOpSet S; S.n = 5; int waves = 0;
        S.ops[0] = {fuse_W1, 768, vall, fuse_b1, nullptr, fpb, 256, 768};
        S.ops[1] = {pool_W1, 768, vall, pool_b1, nullptr, fpb + 256, 128, 256};
        S.ops[2] = {gru_Wih, 264, fuse_b2, gru_bih, gru_bhh, gbias, 512, 256};
        S.ops[3] = {gru_Wih + 512 * 264, 264, fuse_b2, gru_bih + 512, nullptr, gbias + 512, 256, 256};
        S.ops[4] = {nullptr, 0, nullptr, gru_bhh + 512, nullptr, gbias + 768, 256, 0};
        for (int i = 0; i < S.n; i++) { S.waves[i] = S.ops[i].I; waves += S.ops[i].I; }
        mv_ops<<<(waves + 3) / 4, 256, 0, stream>>>(S);
    }
    {   // T3
        TOpSet S; S.n = 0; int grid = 0;
        auto add = [&](TOp o) { S.tiles[S.n] = tilesOf(o); grid += S.tiles[S.n]; S.ops[S.n++] = o; };
        // FPW rows 0..256 (fuse)
        add({0, fuse_W1, 768, 1, own_W, 1, 32, FPW, 360, 256, 32, 256, 1, 0, 0, 0});
        add({3, nullptr, 0, 0, nullptr, 0, 0, FPW + 32, 360, 256, 72, 0, 1, 0, 0, 0});
        add({0, fuse_W1 + 256, 768, 1, WoVA, 1, 128, FPW + 104, 360, 256, 128, 256, 1, 0, 0, 0});
        add({0, fuse_W1 + 512, 768, 1, WoVE, 1, 128, FPW + 232, 360, 256, 128, 256, 1, 0, 0, 0});
        // FPW rows 256..384 (pool)
        add({0, pool_W1, 768, 1, own_W, 1, 32, FPW + 256 * 360, 360, 128, 32, 256, 1, 0, 0, 0});
        add({0, pool_W1 + 256, 768, 1, ally_W, 1, 32, FPW + 256 * 360 + 32, 360, 128, 32, 256, 1, 0, 0, 0});
        add({0, pool_W1 + 512, 768, 1, en_W, 1, 32, FPW + 256 * 360 + 64, 360, 128, 32, 256, 1, 0, 0, 0});
        add({0, pool_W1 + 256, 768, 1, ally_b, 0, 1, FPW + 256 * 360 + 96, 360, 128, 1, 256, 1, 0, 0, 0});
        add({0, pool_W1 + 512, 768, 1, en_b, 0, 1, FPW + 256 * 360 + 97, 360, 128, 1, 256, 1, 0, 0, 0});
        add({3, nullptr, 0, 0, nullptr, 0, 0, FPW + 256 * 360 + 98, 360, 128, 262, 0, 1, 0, 0, 0});
        // WGRU rows 0..512 (r,z)
        add({0, gru_Wih, 264, 1, fuse_W2, 1, 256, WGRU, 520, 512, 256, 256, 1, 0, 0, 0});
        add({2, gru_Wih + 256, 264, 1, nullptr, 0, 0, WGRU + 256, 520, 512, 8, 0, 1, 0, 0, 0});
        add({2, gru_Whh, 256, 1, nullptr, 0, 0, WGRU + 264, 520, 512, 256, 0, 1, 0, 0, 0});
        // WGRU rows 512..768 (i_n)
        add({0, gru_Wih + 512 * 264, 264, 1, fuse_W2, 1, 256, WGRU + 512 * 520, 520, 256, 256, 256, 1, 0, 0, 0});
        add({2, gru_Wih + 512 * 264 + 256, 264, 1, nullptr, 0, 0, WGRU + 512 * 520 + 256, 520, 256, 8, 0, 1, 0, 0, 0});
        add({3, nullptr, 0, 0, nullptr, 0, 0, WGRU + 512 * 520 + 264, 520, 256, 256, 0, 1, 0, 0, 0});
        // WGRU rows 768..1024 (h_n)
        add({3, nullptr, 0, 0, nullptr, 0, 0, WGRU + 768 * 520, 520, 256, 264, 0, 1, 0, 0, 0});
        add({2, gru_Whh + 512 * 256, 256, 1, nullptr, 0, 0, WGRU + 768 * 520 + 264, 520, 256, 256, 0, 1, 0, 0, 0});
        // QWSW
        add({0, Wkpp, 1, 32, qp_W, 1, 264, QWSW, 264, 32, 264, 256, 1, 0, 0, 0});
        add({0, bkpp, 0, 1, qp_W, 1, 264, QWSW + 32 * 264, 264, 1, 264, 256, 1, 0, 0, 0});
        add({2, qn_W, 256, 1, nullptr, 0, 0, QWSW + 33 * 264, 264, 6, 256, 0, 1, 0, 0, 0});
        add({3, nullptr, 0, 0, nullptr, 0, 0, QWSW + 33 * 264 + 256, 264, 6, 8, 0, 1, 0, 0, 0});
        add({3, nullptr, 0, 0, nullptr, 0, 0, QWSW + 39 * 264, 264, 1, 264, 0, 1, 0, 0, 0});
        // WQKSO bf16
        add({0, WQKS_AE, 256, 1, own_W, 1, 32, WQKSO, 32, 256, 32, 256, 1, 0, 0, 0});
        // rpW = role_W1 @ pool_W2
        add({0, role_W1, 128, 1, pool_W2, 1, 128, rpW, 128, 128, 128, 128, 1, 0, 0, 0});
        compose_tiled<<<grid, 256, 0, stream>>>(S);
    }

    auto gemm = [&](const unsigned short* A, int lda, const unsigned short* Wm, const float* bias,
                    unsigned short* C, int ldc, int N, int K, int act) {
        gemm_bf16<<<dim3(MROWS / 128, (N + 127) / 128), 256, 0, stream>>>(A, lda, Wm, bias, C, ldc, N, K, act, zbuf);
    };

    // ---- main chain ----
    gemm(OWNb, 32, WQKSO, qksb, QKSb, 256, 256, 32, 0);               // QKS
    glue_attn<<<MROWS / 4, 256, 0, stream>>>(ally_feats, enemy_feats, own_feats, QKSb, X);
    gemm(X, 360, FPW, fpb, FPC, 384, 384, 360, 1);                    // fuse1+pool1 (+gelu)
    ln_fp<<<MROWS, 384, 0, stream>>>(FPC, fuse_g1, fuse_be1, pool_g1, pool_be1, XG, T2b);
    gemm(T2b, 128, rpW, rpb, T3b, 128, 128, 128, 1);                  // role1 (pool_W2 folded) + gelu
    ln_role<<<MROWS / 32, 256, 0, stream>>>(T3b, role_g1, role_be1, role_W2, role_b2, rln_g, rln_b, XG);
    gemm(XG, 520, WGRU, gbias, GIb, 1024, 1024, 520, 0);              // merged GRU gemm
    glue_gru<<<MROWS, 256, 0, stream>>>(GIb, hidden, Hout, XQ, XG);
    gemm(XQ, 264, QWSW, nullptr, QWSb, 40, 40, 264, 0);               // qws + c0 + q_normal
    glue_final<<<MROWS / 8, 256, 0, stream>>>(QWSb, enemy_feats, qn_b, Qout);
}